// Round 8
// baseline (62209.161 us; speedup 1.0000x reference)
//
#include <hip/hip_runtime.h>
#include <math.h>

#define B_ 64
#define T_ 32
#define N_ 12
#define NS_ 132
#define KN_ 11
#define TEMP_ 1.375f   // K_NEIGH / sqrt(ATTN) = 11/8
#define NBLK 624

typedef unsigned short u16;
typedef __attribute__((ext_vector_type(8))) short bf16x8;
typedef __attribute__((ext_vector_type(8))) unsigned short u16x8;
typedef __attribute__((ext_vector_type(4))) float f32x4;

__device__ __forceinline__ float sigm(float x) { return 1.f / (1.f + __expf(-x)); }
__device__ __forceinline__ float ftanh(float x) {
    float a = fabsf(x);
    float e = __expf(-2.f * a);
    float t = (1.f - e) / (1.f + e);
    return copysignf(t, x);
}
__device__ __forceinline__ u16 f2bf(float x) {
    union { float f; unsigned u; } v; v.f = x;
    unsigned r = v.u + 0x7fffu + ((v.u >> 16) & 1u);
    return (u16)(r >> 16);
}
__device__ __forceinline__ float bf2f(u16 h) {
    union { unsigned u; float f; } v; v.u = ((unsigned)h) << 16; return v.f;
}
__device__ __forceinline__ int origcol(int j) {
    return ((j >> 4) & 3) * 256 + ((j >> 6) << 4) + (j & 15);
}

// Fragment layout for M[R][K] (A/B operand of mfma 16x16x32 bf16):
//   tile = (r>>4)*(K/32) + (k>>5); lane = ((k>>3)&3)*16 + (r&15); elem = k&7
//   flat u16 index = tile*512 + lane*8 + elem
// Row-slice read (k 8-aligned): 8 contiguous u16 at
//   ((r>>4)*nkc + (k>>5))*512 + (((k>>3)&3)*16 + (r&15))*8
__device__ __forceinline__ const u16* frag_row8(const u16* basef, int row, int k, int nkc) {
    return basef + (((size_t)(row >> 4) * nkc + (k >> 5)) * 512)
                 + ((((k >> 3) & 3) * 16 + (row & 15)) * 8);
}

// device-scope grid barrier: monotonic counter, no reset
__device__ __forceinline__ void gridbar(unsigned* cnt, unsigned target) {
    __syncthreads();
    if (threadIdx.x == 0) {
        __threadfence();   // release: flush this CU/L2 so other XCDs see our writes
        __hip_atomic_fetch_add(cnt, 1u, __ATOMIC_ACQ_REL, __HIP_MEMORY_SCOPE_AGENT);
        while (__hip_atomic_load(cnt, __ATOMIC_ACQUIRE, __HIP_MEMORY_SCOPE_AGENT) < target)
            __builtin_amdgcn_s_sleep(8);
        __threadfence();   // acquire: invalidate L1/L2 before reading others' writes
    }
    __syncthreads();
}

// ---------------------------------------------------------------------------
// prep: all weights -> bf16 fragment layout, fused biases. (unchanged)
// ---------------------------------------------------------------------------
__global__ __launch_bounds__(256) void prep_kernel(
    const float* __restrict__ te_Wih, const float* __restrict__ te_Whh,
    const float* __restrict__ te_bih, const float* __restrict__ te_bhh,
    const float* __restrict__ se_Wih, const float* __restrict__ se_Whh,
    const float* __restrict__ se_bih, const float* __restrict__ se_bhh,
    const float* __restrict__ nr_Wih, const float* __restrict__ nr_Whh,
    const float* __restrict__ nr_bih, const float* __restrict__ nr_bhh,
    const float* __restrict__ Wq, const float* __restrict__ Wk,
    const float* __restrict__ W_edge,
    u16* __restrict__ Wf_t, u16* __restrict__ Wf_s, u16* __restrict__ Wf_n,
    float* __restrict__ bs_t, float* __restrict__ bs_s, float* __restrict__ bs_n,
    u16* __restrict__ Wqf, u16* __restrict__ Wkqf, u16* __restrict__ Wef)
{
    int idx = blockIdx.x * 256 + threadIdx.x;
    if (idx < 49152) {
        int l = idx & 63, kc = (idx >> 6) % 12, jb16 = idx / 768;
        int j = jb16 * 16 + (l & 15);
        int c = origcol(j);
        int k0 = kc * 32 + (l >> 4) * 8;
        u16x8 vt, vs;
        #pragma unroll
        for (int i = 0; i < 8; ++i) {
            int k = k0 + i;
            vt[i] = f2bf((k < 128) ? te_Wih[c * 128 + k] : te_Whh[c * 256 + (k - 128)]);
            vs[i] = f2bf((k < 128) ? se_Wih[c * 128 + k] : se_Whh[c * 256 + (k - 128)]);
        }
        *(u16x8*)(Wf_t + (size_t)idx * 8) = vt;
        *(u16x8*)(Wf_s + (size_t)idx * 8) = vs;
    }
    if (idx < 65536) {
        int l = idx & 63, kc = (idx >> 6) & 15, jb16 = idx >> 10;
        int j = jb16 * 16 + (l & 15);
        int c = origcol(j);
        int k0 = kc * 32 + (l >> 4) * 8;
        u16x8 vn;
        #pragma unroll
        for (int i = 0; i < 8; ++i) {
            int k = k0 + i;
            vn[i] = f2bf((k < 256) ? nr_Wih[c * 256 + k] : nr_Whh[c * 256 + (k - 256)]);
        }
        *(u16x8*)(Wf_n + (size_t)idx * 8) = vn;
    }
    if (idx < 1024) {
        int c = origcol(idx);
        bs_t[idx] = te_bih[c] + te_bhh[c];
        bs_s[idx] = se_bih[c] + se_bhh[c];
        bs_n[idx] = nr_bih[c] + nr_bhh[c];
    }
    if (idx < 2048) {
        int l = idx & 63, tile = idx >> 6;
        int a = (tile >> 3) * 16 + (l & 15);
        int k0 = (tile & 7) * 32 + (l >> 4) * 8;
        u16x8 v;
        #pragma unroll
        for (int i = 0; i < 8; ++i) v[i] = f2bf(Wq[a * 256 + k0 + i]);
        *(u16x8*)(Wqf + (size_t)idx * 8) = v;
    }
    if (idx < 2048) {
        int l = idx & 63, tile = idx >> 6;
        int j = (tile >> 1) * 16 + (l & 15);
        int a0 = (tile & 1) * 32 + (l >> 4) * 8;
        u16x8 v;
        #pragma unroll
        for (int i = 0; i < 8; ++i) v[i] = f2bf(Wk[(a0 + i) * 256 + j]);
        *(u16x8*)(Wkqf + (size_t)idx * 8) = v;
    }
    if (idx < 8192) {
        int l = idx & 63, tile = idx >> 6;
        int c = (tile >> 4) * 16 + (l & 15);
        int k0 = (tile & 15) * 32 + (l >> 4) * 8;
        u16x8 v;
        #pragma unroll
        for (int i = 0; i < 8; ++i) v[i] = f2bf(W_edge[c * 512 + k0 + i]);
        *(u16x8*)(Wef + (size_t)idx * 8) = v;
    }
}

// ---------------------------------------------------------------------------
// persist_kernel: the entire T-step recurrence in one launch.
// blocks 0..527  spatial LSTM tiles (XCD-chunked), 528..575 temporal LSTM,
// blocks 576..623 attn + edge + node LSTM (one per 16 node-rows).
// Per iter i: lstm(i) || node(i-1); grid barrier after iters 0..T-1.
// c-states in registers; h_node + ein in LDS; embeddings inline.
// ---------------------------------------------------------------------------
__global__ __launch_bounds__(256, 3) void persist_kernel(
    const float* __restrict__ es, const float* __restrict__ et,
    const float* __restrict__ nodes,
    const float* __restrict__ W_se, const float* __restrict__ b_se,
    const float* __restrict__ W_te, const float* __restrict__ b_te,
    const float* __restrict__ W_node, const float* __restrict__ b_node,
    const u16* __restrict__ Wf_t, const float* __restrict__ bs_t,
    const u16* __restrict__ Wf_s, const float* __restrict__ bs_s,
    const u16* __restrict__ Wf_n, const float* __restrict__ bs_n,
    u16* __restrict__ htf0, u16* __restrict__ htf1,
    u16* __restrict__ hsf0, u16* __restrict__ hsf1,
    u16* __restrict__ hist,
    const u16* __restrict__ Wqf, const float* __restrict__ bq,
    const u16* __restrict__ Wkqf, const float* __restrict__ bk,
    const u16* __restrict__ Wef, const float* __restrict__ b_edge,
    unsigned* __restrict__ cnt)
{
    const int tid = threadIdx.x;
    const int l = tid & 63, l15 = l & 15;
    const size_t lo8 = (size_t)l * 8;
    const int wid = tid >> 6;

    __shared__ float q_lds[16][68];
    __shared__ float shbuf[16][260];
    __shared__ float sc_lds[16][12];
    __shared__ float w_lds[16][12];
    __shared__ float qb_lds[16];
    __shared__ u16 einL[2048];
    __shared__ u16 hnfL[4096];      // h_node frags for this block's 16 rows

    if ((int)blockIdx.x < 576) {
        // ===================== LSTM block =====================
        const int lb = blockIdx.x;
        const bool spatial = lb < 528;
        int rb, jc;
        if (spatial) { int orig = (lb & 7) * 66 + (lb >> 3); rb = orig >> 3; jc = orig & 7; }
        else         { int q = lb - 528;                      rb = q >> 3;    jc = q & 7; }
        const int ns = spatial ? NS_ : N_;
        const float* E    = spatial ? es : et;
        const float* Wemb = spatial ? W_se : W_te;
        const float* bemb = spatial ? b_se : b_te;
        const u16* Wf     = spatial ? Wf_s : Wf_t;
        const float* bs   = spatial ? bs_s : bs_t;
        u16* hb0 = spatial ? hsf0 : htf0;
        u16* hb1 = spatial ? hsf1 : htf1;

        const int wm = wid >> 1, wn = wid & 1;
        const int rb16 = rb * 8 + wm * 4;
        const int jb16 = jc * 8 + wn * 4;

        float biasv[4];
        #pragma unroll
        for (int g = 0; g < 4; ++g) biasv[g] = bs[jc * 128 + wn * 64 + g * 16 + l15];

        size_t ebase[4];
        #pragma unroll
        for (int mf = 0; mf < 4; ++mf) {
            int row = (rb16 + mf) * 16 + l15;
            int b = row / ns, s = row - b * ns;
            ebase[mf] = ((size_t)b * T_ * ns + s) * 2;
        }

        float creg[4][4];
        #pragma unroll
        for (int mf = 0; mf < 4; ++mf)
            #pragma unroll
            for (int r = 0; r < 4; ++r) creg[mf][r] = 0.f;

        const int cell = (jc * 2 + wn) * 16 + l15;
        const int rofs = (l >> 4) << 2;
        const int cpart = (cell >> 5) * 512 + ((cell >> 3) & 3) * 128 + (cell & 7);
        const int kemb0 = (l >> 4) * 8;

        for (int i = 0; i <= T_; ++i) {
            if (i < T_) {
                const u16* Hf = (i & 1) ? hb1 : hb0;
                u16*       Hc = (i & 1) ? hb0 : hb1;

                float e0[4], e1[4];
                #pragma unroll
                for (int mf = 0; mf < 4; ++mf) {
                    const float* ep = E + ebase[mf] + (size_t)i * ns * 2;
                    e0[mf] = ep[0]; e1[mf] = ep[1];
                }

                f32x4 acc[4][4];
                #pragma unroll
                for (int mf = 0; mf < 4; ++mf)
                    #pragma unroll
                    for (int g = 0; g < 4; ++g)
                        acc[mf][g] = (f32x4){biasv[g], biasv[g], biasv[g], biasv[g]};

                #pragma unroll
                for (int kc = 0; kc < 12; ++kc) {
                    bf16x8 a[4], b[4];
                    if (kc < 4) {
                        #pragma unroll
                        for (int mf = 0; mf < 4; ++mf) {
                            u16x8 v;
                            #pragma unroll
                            for (int e = 0; e < 8; ++e) {
                                int k = kc * 32 + kemb0 + e;
                                float x = fmaf(e0[mf], Wemb[k * 2],
                                          fmaf(e1[mf], Wemb[k * 2 + 1], bemb[k]));
                                v[e] = f2bf(fmaxf(x, 0.f));
                            }
                            a[mf] = (bf16x8)v;
                        }
                    } else {
                        #pragma unroll
                        for (int mf = 0; mf < 4; ++mf)
                            a[mf] = *(const bf16x8*)(Hf + (((size_t)(rb16 + mf)) * 8 + (kc - 4)) * 512 + lo8);
                    }
                    #pragma unroll
                    for (int g = 0; g < 4; ++g)
                        b[g] = *(const bf16x8*)(Wf + (((size_t)(jb16 + g)) * 12 + kc) * 512 + lo8);
                    #pragma unroll
                    for (int mf = 0; mf < 4; ++mf)
                        #pragma unroll
                        for (int g = 0; g < 4; ++g)
                            acc[mf][g] = __builtin_amdgcn_mfma_f32_16x16x32_bf16(a[mf], b[g], acc[mf][g], 0, 0, 0);
                }

                #pragma unroll
                for (int mf = 0; mf < 4; ++mf) {
                    #pragma unroll
                    for (int r = 0; r < 4; ++r) {
                        float gi = acc[mf][0][r], gf = acc[mf][1][r];
                        float gg = acc[mf][2][r], go = acc[mf][3][r];
                        float c2 = sigm(gf) * creg[mf][r] + sigm(gi) * ftanh(gg);
                        creg[mf][r] = c2;
                        float h2 = sigm(go) * ftanh(c2);
                        Hc[(size_t)(rb16 + mf) * 4096 + cpart + (rofs + r) * 8] = f2bf(h2);
                    }
                }
            }
            if (i < T_) gridbar(cnt, (unsigned)NBLK * (i + 1));
        }
        return;
    }

    // ===================== node + attn block =====================
    const int rb16n = blockIdx.x - 576;   // 0..47

    for (int x = tid; x < 4096; x += 256) hnfL[x] = 0;   // h_node(0) = 0

    float cn[4][4];
    #pragma unroll
    for (int ch = 0; ch < 4; ++ch)
        #pragma unroll
        for (int r = 0; r < 4; ++r) cn[ch][r] = 0.f;

    // per-lane nin source (row fixed)
    const int rowN = rb16n * 16 + l15;
    const int bN = rowN / 12, nN = rowN - bN * 12;
    const size_t ninbase = ((size_t)bN * T_ * 12 + nN) * 2;
    const int kemb0 = (l >> 4) * 8;
    const int rofs = (l >> 4) << 2;

    __syncthreads();

    for (int i = 0; i <= T_; ++i) {
        if (i >= 1) {
            const int tn = i - 1;
            const u16* htfp = (i & 1) ? htf1 : htf0;
            const u16* hsfp = (i & 1) ? hsf1 : hsf0;

            if (wid == 0) {   // q = h_t @ Wq^T
                f32x4 qa[4];
                #pragma unroll
                for (int jb = 0; jb < 4; ++jb) qa[jb] = (f32x4){0.f, 0.f, 0.f, 0.f};
                #pragma unroll
                for (int kc = 0; kc < 8; ++kc) {
                    bf16x8 af = *(const bf16x8*)(htfp + ((size_t)rb16n * 8 + kc) * 512 + lo8);
                    #pragma unroll
                    for (int jb = 0; jb < 4; ++jb) {
                        bf16x8 bf = *(const bf16x8*)(Wqf + ((size_t)(jb * 8 + kc)) * 512 + lo8);
                        qa[jb] = __builtin_amdgcn_mfma_f32_16x16x32_bf16(af, bf, qa[jb], 0, 0, 0);
                    }
                }
                #pragma unroll
                for (int jb = 0; jb < 4; ++jb) {
                    int a = jb * 16 + l15;
                    #pragma unroll
                    for (int r = 0; r < 4; ++r)
                        q_lds[(l >> 4) * 4 + r][a] = qa[jb][r] + bq[a];
                }
            }
            __syncthreads();
            if (wid == 0) {   // qk = q @ Wk
                #pragma unroll
                for (int half = 0; half < 2; ++half) {
                    f32x4 ka[8];
                    #pragma unroll
                    for (int jb = 0; jb < 8; ++jb) ka[jb] = (f32x4){0.f, 0.f, 0.f, 0.f};
                    #pragma unroll
                    for (int kc = 0; kc < 2; ++kc) {
                        int a0 = kc * 32 + (l >> 4) * 8;
                        bf16x8 af;
                        #pragma unroll
                        for (int e = 0; e < 8; ++e)
                            ((u16*)&af)[e] = f2bf(q_lds[l15][a0 + e]);
                        #pragma unroll
                        for (int jb = 0; jb < 8; ++jb) {
                            bf16x8 bf = *(const bf16x8*)(Wkqf + ((size_t)((half * 8 + jb) * 2 + kc)) * 512 + lo8);
                            ka[jb] = __builtin_amdgcn_mfma_f32_16x16x32_bf16(af, bf, ka[jb], 0, 0, 0);
                        }
                    }
                    #pragma unroll
                    for (int jb = 0; jb < 8; ++jb)
                        #pragma unroll
                        for (int r = 0; r < 4; ++r)
                            shbuf[(l >> 4) * 4 + r][(half * 8 + jb) * 16 + l15] = ka[jb][r];
                }
            }
            if (wid == 1 && l < 16) {
                float s = 0.f;
                for (int a = 0; a < 64; ++a) s = fmaf(q_lds[l][a], bk[a], s);
                qb_lds[l] = s;
            }
            __syncthreads();
            if (tid < 176) {   // scores, reading h_s frags directly
                int row = tid / 11, kk = tid - row * 11;
                int r = rb16n * 16 + row;
                int srow = (r / 12) * 132 + (r % 12) * 11 + kk;
                float s = 0.f;
                #pragma unroll
                for (int k = 0; k < 256; k += 8) {
                    u16x8 v = *(const u16x8*)frag_row8(hsfp, srow, k, 8);
                    #pragma unroll
                    for (int e = 0; e < 8; ++e) s = fmaf(shbuf[row][k + e], bf2f(v[e]), s);
                }
                sc_lds[row][kk] = (s + qb_lds[row]) * TEMP_;
            }
            __syncthreads();
            if (tid < 16) {
                float m = sc_lds[tid][0];
                #pragma unroll
                for (int kk = 1; kk < 11; ++kk) m = fmaxf(m, sc_lds[tid][kk]);
                float ssum = 0.f;
                float wv[11];
                #pragma unroll
                for (int kk = 0; kk < 11; ++kk) { wv[kk] = __expf(sc_lds[tid][kk] - m); ssum += wv[kk]; }
                float inv = 1.f / ssum;
                #pragma unroll
                for (int kk = 0; kk < 11; ++kk) w_lds[tid][kk] = wv[kk] * inv;
            }
            __syncthreads();
            {   // h_attn -> shbuf
                int row = tid >> 4, c0 = (tid & 15) * 16;
                int r = rb16n * 16 + row;
                int sbase = (r / 12) * 132 + (r % 12) * 11;
                float hacc[16];
                #pragma unroll
                for (int e = 0; e < 16; ++e) hacc[e] = 0.f;
                #pragma unroll
                for (int kk = 0; kk < 11; ++kk) {
                    float wv = w_lds[row][kk];
                    int srow = sbase + kk;
                    u16x8 v0 = *(const u16x8*)frag_row8(hsfp, srow, c0, 8);
                    u16x8 v1 = *(const u16x8*)frag_row8(hsfp, srow, c0 + 8, 8);
                    #pragma unroll
                    for (int e = 0; e < 8; ++e) {
                        hacc[e]     = fmaf(wv, bf2f(v0[e]), hacc[e]);
                        hacc[8 + e] = fmaf(wv, bf2f(v1[e]), hacc[8 + e]);
                    }
                }
                #pragma unroll
                for (int e = 0; e < 16; ++e) shbuf[row][c0 + e] = hacc[e];
            }
            __syncthreads();
            {   // ein = [h_t | h_attn] @ W_edge^T -> einL
                f32x4 ea[2];
                ea[0] = (f32x4){0.f, 0.f, 0.f, 0.f};
                ea[1] = (f32x4){0.f, 0.f, 0.f, 0.f};
                #pragma unroll
                for (int kc = 0; kc < 16; ++kc) {
                    bf16x8 af;
                    if (kc < 8) {
                        af = *(const bf16x8*)(htfp + ((size_t)rb16n * 8 + kc) * 512 + lo8);
                    } else {
                        int k0 = (kc - 8) * 32 + (l >> 4) * 8;
                        #pragma unroll
                        for (int e = 0; e < 8; ++e)
                            ((u16*)&af)[e] = f2bf(shbuf[l15][k0 + e]);
                    }
                    #pragma unroll
                    for (int j2 = 0; j2 < 2; ++j2) {
                        bf16x8 bf = *(const bf16x8*)(Wef + ((size_t)((wid * 2 + j2) * 16 + kc)) * 512 + lo8);
                        ea[j2] = __builtin_amdgcn_mfma_f32_16x16x32_bf16(af, bf, ea[j2], 0, 0, 0);
                    }
                }
                #pragma unroll
                for (int j2 = 0; j2 < 2; ++j2) {
                    int cell = (wid * 2 + j2) * 16 + l15;
                    #pragma unroll
                    for (int r = 0; r < 4; ++r) {
                        int row = (l >> 4) * 4 + r;
                        float v = ea[j2][r] + b_edge[cell];
                        v = v > 0.f ? v : 0.f;
                        einL[(size_t)(cell >> 5) * 512 + (((cell >> 3) & 3) * 16 + row) * 8 + (cell & 7)] = f2bf(v);
                    }
                }
            }
            __syncthreads();
            {   // node LSTM GEMM (static acc indices) + epilogue
                f32x4 na[4][4];
                #pragma unroll
                for (int ch = 0; ch < 4; ++ch)
                    #pragma unroll
                    for (int g = 0; g < 4; ++g) {
                        float bv = bs_n[(wid * 16 + ch * 4 + g) * 16 + l15];
                        na[ch][g] = (f32x4){bv, bv, bv, bv};
                    }
                #pragma unroll
                for (int kc = 0; kc < 16; ++kc) {
                    bf16x8 af;
                    if (kc < 4) {        // nin inline from nodes
                        const float* np = nodes + ninbase + (size_t)tn * 12 * 2;
                        float n0 = np[0], n1 = np[1];
                        u16x8 v;
                        #pragma unroll
                        for (int e = 0; e < 8; ++e) {
                            int k = kc * 32 + kemb0 + e;
                            float x = fmaf(n0, W_node[k * 2], fmaf(n1, W_node[k * 2 + 1], b_node[k]));
                            v[e] = f2bf(fmaxf(x, 0.f));
                        }
                        af = (bf16x8)v;
                    } else if (kc < 8) {
                        af = *(const bf16x8*)(einL + (size_t)(kc - 4) * 512 + lo8);
                    } else {
                        af = *(const bf16x8*)(hnfL + (size_t)(kc - 8) * 512 + lo8);
                    }
                    const u16* wb = Wf_n + (((size_t)(wid * 16)) * 16 + kc) * 512 + lo8;
                    #pragma unroll
                    for (int ch = 0; ch < 4; ++ch)
                        #pragma unroll
                        for (int g = 0; g < 4; ++g) {
                            bf16x8 bf = *(const bf16x8*)(wb + (size_t)(ch * 4 + g) * 16 * 512);
                            na[ch][g] = __builtin_amdgcn_mfma_f32_16x16x32_bf16(af, bf, na[ch][g], 0, 0, 0);
                        }
                }
                __syncthreads();   // all waves done READING hnfL before overwrite
                u16* hist1 = hist + (size_t)i * 768 * 256;   // slot tn+1 = i
                #pragma unroll
                for (int ch = 0; ch < 4; ++ch) {
                    int cell = (wid * 4 + ch) * 16 + l15;
                    int cpart = (cell >> 5) * 512 + ((cell >> 3) & 3) * 128 + (cell & 7);
                    #pragma unroll
                    for (int r = 0; r < 4; ++r) {
                        int rlow = rofs + r;
                        float gi = na[ch][0][r], gf = na[ch][1][r];
                        float gg = na[ch][2][r], go = na[ch][3][r];
                        float c2 = sigm(gf) * cn[ch][r] + sigm(gi) * ftanh(gg);
                        cn[ch][r] = c2;
                        float h2 = sigm(go) * ftanh(c2);
                        u16 hb = f2bf(h2);
                        hist1[((size_t)rb16n * 16 + rlow) * 256 + cell] = hb;
                        hnfL[cpart + rlow * 8] = hb;
                    }
                }
            }
        }
        if (i < T_) gridbar(cnt, (unsigned)NBLK * (i + 1));
    }
}

// out[b,t,n,q] = hist[t+1] . W_out^T + b_out
__global__ __launch_bounds__(256) void out_kernel(
    const u16* __restrict__ hist1, const float* __restrict__ W_out,
    const float* __restrict__ b_out, float* __restrict__ out)
{
    const int lane = threadIdx.x & 63;
    const int grp = threadIdx.x >> 6;
    for (int ridx = blockIdx.x * 4 + grp; ridx < 32 * 768; ridx += gridDim.x * 4) {
        int t = ridx / 768, row = ridx % 768;
        int b = row / 12, n = row % 12;
        const u16* h = &hist1[(size_t)ridx * 256];
        float hv[4];
        #pragma unroll
        for (int i = 0; i < 4; ++i) hv[i] = bf2f(h[i * 64 + lane]);
        #pragma unroll
        for (int q = 0; q < 5; ++q) {
            float s = 0.f;
            #pragma unroll
            for (int i = 0; i < 4; ++i) s = fmaf(hv[i], W_out[q * 256 + i * 64 + lane], s);
            #pragma unroll
            for (int off = 32; off > 0; off >>= 1) s += __shfl_down(s, off, 64);
            if (lane == 0)
                out[(((size_t)b * T_ + t) * N_ + n) * 5 + q] = s + b_out[q];
        }
    }
}

extern "C" void kernel_launch(void* const* d_in, const int* in_sizes, int n_in,
                              void* d_out, int out_size, void* d_ws, size_t ws_size,
                              hipStream_t stream)
{
    const float* nodes = (const float*)d_in[0];
    const float* et    = (const float*)d_in[1];
    const float* es    = (const float*)d_in[2];
    const float* W_te = (const float*)d_in[3];  const float* b_te = (const float*)d_in[4];
    const float* te_Wih = (const float*)d_in[5]; const float* te_Whh = (const float*)d_in[6];
    const float* te_bih = (const float*)d_in[7]; const float* te_bhh = (const float*)d_in[8];
    const float* W_se = (const float*)d_in[9];  const float* b_se = (const float*)d_in[10];
    const float* se_Wih = (const float*)d_in[11]; const float* se_Whh = (const float*)d_in[12];
    const float* se_bih = (const float*)d_in[13]; const float* se_bhh = (const float*)d_in[14];
    const float* Wq = (const float*)d_in[15]; const float* bq = (const float*)d_in[16];
    const float* Wk = (const float*)d_in[17]; const float* bk = (const float*)d_in[18];
    const float* W_node = (const float*)d_in[19]; const float* b_node = (const float*)d_in[20];
    const float* W_edge = (const float*)d_in[21]; const float* b_edge = (const float*)d_in[22];
    const float* nr_Wih = (const float*)d_in[23]; const float* nr_Whh = (const float*)d_in[24];
    const float* nr_bih = (const float*)d_in[25]; const float* nr_bhh = (const float*)d_in[26];
    const float* W_out = (const float*)d_in[27]; const float* b_out = (const float*)d_in[28];

    char* base = (char*)d_ws;
    size_t off = 0;
    auto A = [&](size_t bytes) { char* p = base + off; off += (bytes + 255) & ~(size_t)255; return p; };

    // zero region: barrier counter + t=0 h frag states (contiguous)
    unsigned* cnt = (unsigned*)A(256);
    u16* htf0 = (u16*)A(768 * 256 * 2);
    u16* hsf0 = (u16*)A((size_t)8448 * 256 * 2);
    size_t zero_bytes = off;
    u16* htf1 = (u16*)A(768 * 256 * 2);
    u16* hsf1 = (u16*)A((size_t)8448 * 256 * 2);
    u16* hist = (u16*)A((size_t)33 * 768 * 256 * 2);
    u16* Wf_t = (u16*)A(1024 * 384 * 2);
    u16* Wf_s = (u16*)A(1024 * 384 * 2);
    u16* Wf_n = (u16*)A(1024 * 512 * 2);
    float* bs_t = (float*)A(1024 * 4);
    float* bs_s = (float*)A(1024 * 4);
    float* bs_n = (float*)A(1024 * 4);
    u16* Wqf  = (u16*)A(2048 * 8 * 2);
    u16* Wkqf = (u16*)A(2048 * 8 * 2);
    u16* Wef  = (u16*)A(8192 * 8 * 2);
    (void)ws_size;

    hipMemsetAsync(base, 0, zero_bytes, stream);

    prep_kernel<<<256, 256, 0, stream>>>(
        te_Wih, te_Whh, te_bih, te_bhh, se_Wih, se_Whh, se_bih, se_bhh,
        nr_Wih, nr_Whh, nr_bih, nr_bhh, Wq, Wk, W_edge,
        Wf_t, Wf_s, Wf_n, bs_t, bs_s, bs_n, Wqf, Wkqf, Wef);

    persist_kernel<<<NBLK, 256, 0, stream>>>(
        es, et, nodes,
        W_se, b_se, W_te, b_te, W_node, b_node,
        Wf_t, bs_t, Wf_s, bs_s, Wf_n, bs_n,
        htf0, htf1, hsf0, hsf1, hist,
        Wqf, bq, Wkqf, bk, Wef, b_edge, cnt);

    out_kernel<<<1536, 256, 0, stream>>>(hist + (size_t)768 * 256, W_out, b_out, (float*)d_out);
}

// Round 9
// 9520.159 us; speedup vs baseline: 6.5345x; 6.5345x over previous
//
#include <hip/hip_runtime.h>
#include <math.h>

#define B_ 64
#define T_ 32
#define N_ 12
#define NS_ 132
#define KN_ 11
#define TEMP_ 1.375f   // K_NEIGH / sqrt(ATTN) = 11/8
#define NBLK 624

typedef unsigned short u16;
typedef __attribute__((ext_vector_type(8))) short bf16x8;
typedef __attribute__((ext_vector_type(8))) unsigned short u16x8;
typedef __attribute__((ext_vector_type(4))) float f32x4;

__device__ __forceinline__ float sigm(float x) { return 1.f / (1.f + __expf(-x)); }
__device__ __forceinline__ float ftanh(float x) {
    float a = fabsf(x);
    float e = __expf(-2.f * a);
    float t = (1.f - e) / (1.f + e);
    return copysignf(t, x);
}
__device__ __forceinline__ u16 f2bf(float x) {
    union { float f; unsigned u; } v; v.f = x;
    unsigned r = v.u + 0x7fffu + ((v.u >> 16) & 1u);
    return (u16)(r >> 16);
}
__device__ __forceinline__ float bf2f(u16 h) {
    union { unsigned u; float f; } v; v.u = ((unsigned)h) << 16; return v.f;
}
__device__ __forceinline__ int origcol(int j) {
    return ((j >> 4) & 3) * 256 + ((j >> 6) << 4) + (j & 15);
}

// Fragment layout for M[R][K] (A/B operand of mfma 16x16x32 bf16):
//   tile = (r>>4)*(K/32) + (k>>5); lane = ((k>>3)&3)*16 + (r&15); elem = k&7
//   flat u16 index = tile*512 + lane*8 + elem
__device__ __forceinline__ const u16* frag_row8(const u16* basef, int row, int k, int nkc) {
    return basef + (((size_t)(row >> 4) * nkc + (k >> 5)) * 512)
                 + ((((k >> 3) & 3) * 16 + (row & 15)) * 8);
}

// device-scope grid barrier, monotonic counter.
// RELAXED polling (no per-poll cache invalidate — r8's acquire-per-poll
// invalidated L1/L2 ~continuously: 2.5 GB HBM refetch). Single fence pair
// at the boundary provides release/acquire at barrier granularity.
__device__ __forceinline__ void gridbar(unsigned* cnt, unsigned target) {
    __syncthreads();
    if (threadIdx.x == 0) {
        __threadfence();   // release: my writes visible device-wide
        __hip_atomic_fetch_add(cnt, 1u, __ATOMIC_RELAXED, __HIP_MEMORY_SCOPE_AGENT);
        while (__hip_atomic_load(cnt, __ATOMIC_RELAXED, __HIP_MEMORY_SCOPE_AGENT) < target)
            __builtin_amdgcn_s_sleep(16);
        __threadfence();   // acquire: see everyone's pre-barrier writes
    }
    __syncthreads();
}

// ---------------------------------------------------------------------------
// prep: all weights -> bf16 fragment layout, fused biases.
// ---------------------------------------------------------------------------
__global__ __launch_bounds__(256) void prep_kernel(
    const float* __restrict__ te_Wih, const float* __restrict__ te_Whh,
    const float* __restrict__ te_bih, const float* __restrict__ te_bhh,
    const float* __restrict__ se_Wih, const float* __restrict__ se_Whh,
    const float* __restrict__ se_bih, const float* __restrict__ se_bhh,
    const float* __restrict__ nr_Wih, const float* __restrict__ nr_Whh,
    const float* __restrict__ nr_bih, const float* __restrict__ nr_bhh,
    const float* __restrict__ Wq, const float* __restrict__ Wk,
    const float* __restrict__ W_edge,
    u16* __restrict__ Wf_t, u16* __restrict__ Wf_s, u16* __restrict__ Wf_n,
    float* __restrict__ bs_t, float* __restrict__ bs_s, float* __restrict__ bs_n,
    u16* __restrict__ Wqf, u16* __restrict__ Wkqf, u16* __restrict__ Wef)
{
    int idx = blockIdx.x * 256 + threadIdx.x;
    if (idx < 49152) {
        int l = idx & 63, kc = (idx >> 6) % 12, jb16 = idx / 768;
        int j = jb16 * 16 + (l & 15);
        int c = origcol(j);
        int k0 = kc * 32 + (l >> 4) * 8;
        u16x8 vt, vs;
        #pragma unroll
        for (int i = 0; i < 8; ++i) {
            int k = k0 + i;
            vt[i] = f2bf((k < 128) ? te_Wih[c * 128 + k] : te_Whh[c * 256 + (k - 128)]);
            vs[i] = f2bf((k < 128) ? se_Wih[c * 128 + k] : se_Whh[c * 256 + (k - 128)]);
        }
        *(u16x8*)(Wf_t + (size_t)idx * 8) = vt;
        *(u16x8*)(Wf_s + (size_t)idx * 8) = vs;
    }
    if (idx < 65536) {
        int l = idx & 63, kc = (idx >> 6) & 15, jb16 = idx >> 10;
        int j = jb16 * 16 + (l & 15);
        int c = origcol(j);
        int k0 = kc * 32 + (l >> 4) * 8;
        u16x8 vn;
        #pragma unroll
        for (int i = 0; i < 8; ++i) {
            int k = k0 + i;
            vn[i] = f2bf((k < 256) ? nr_Wih[c * 256 + k] : nr_Whh[c * 256 + (k - 256)]);
        }
        *(u16x8*)(Wf_n + (size_t)idx * 8) = vn;
    }
    if (idx < 1024) {
        int c = origcol(idx);
        bs_t[idx] = te_bih[c] + te_bhh[c];
        bs_s[idx] = se_bih[c] + se_bhh[c];
        bs_n[idx] = nr_bih[c] + nr_bhh[c];
    }
    if (idx < 2048) {
        int l = idx & 63, tile = idx >> 6;
        int a = (tile >> 3) * 16 + (l & 15);
        int k0 = (tile & 7) * 32 + (l >> 4) * 8;
        u16x8 v;
        #pragma unroll
        for (int i = 0; i < 8; ++i) v[i] = f2bf(Wq[a * 256 + k0 + i]);
        *(u16x8*)(Wqf + (size_t)idx * 8) = v;
    }
    if (idx < 2048) {
        int l = idx & 63, tile = idx >> 6;
        int j = (tile >> 1) * 16 + (l & 15);
        int a0 = (tile & 1) * 32 + (l >> 4) * 8;
        u16x8 v;
        #pragma unroll
        for (int i = 0; i < 8; ++i) v[i] = f2bf(Wk[(a0 + i) * 256 + j]);
        *(u16x8*)(Wkqf + (size_t)idx * 8) = v;
    }
    if (idx < 8192) {
        int l = idx & 63, tile = idx >> 6;
        int c = (tile >> 4) * 16 + (l & 15);
        int k0 = (tile & 15) * 32 + (l >> 4) * 8;
        u16x8 v;
        #pragma unroll
        for (int i = 0; i < 8; ++i) v[i] = f2bf(W_edge[c * 512 + k0 + i]);
        *(u16x8*)(Wef + (size_t)idx * 8) = v;
    }
}

// ---------------------------------------------------------------------------
// persist_kernel: entire T-step recurrence in one launch.
// blocks 0..527 spatial LSTM (XCD-chunked), 528..575 temporal LSTM,
// 576..623 attn + edge + node LSTM. Per iter i: lstm(i) || node(i-1).
// ---------------------------------------------------------------------------
__global__ __launch_bounds__(256, 3) void persist_kernel(
    const float* __restrict__ es, const float* __restrict__ et,
    const float* __restrict__ nodes,
    const float* __restrict__ W_se, const float* __restrict__ b_se,
    const float* __restrict__ W_te, const float* __restrict__ b_te,
    const float* __restrict__ W_node, const float* __restrict__ b_node,
    const u16* __restrict__ Wf_t, const float* __restrict__ bs_t,
    const u16* __restrict__ Wf_s, const float* __restrict__ bs_s,
    const u16* __restrict__ Wf_n, const float* __restrict__ bs_n,
    u16* __restrict__ htf0, u16* __restrict__ htf1,
    u16* __restrict__ hsf0, u16* __restrict__ hsf1,
    u16* __restrict__ hist,
    const u16* __restrict__ Wqf, const float* __restrict__ bq,
    const u16* __restrict__ Wkqf, const float* __restrict__ bk,
    const u16* __restrict__ Wef, const float* __restrict__ b_edge,
    unsigned* __restrict__ cnt)
{
    const int tid = threadIdx.x;
    const int l = tid & 63, l15 = l & 15;
    const size_t lo8 = (size_t)l * 8;
    const int wid = tid >> 6;

    __shared__ float q_lds[16][68];
    __shared__ float shbuf[16][260];
    __shared__ float sc_lds[16][12];
    __shared__ float w_lds[16][12];
    __shared__ float qb_lds[16];
    __shared__ u16 einL[2048];
    __shared__ u16 hnfL[4096];

    if ((int)blockIdx.x < 576) {
        // ===================== LSTM block =====================
        const int lb = blockIdx.x;
        const bool spatial = lb < 528;
        int rb, jc;
        if (spatial) { int orig = (lb & 7) * 66 + (lb >> 3); rb = orig >> 3; jc = orig & 7; }
        else         { int q = lb - 528;                      rb = q >> 3;    jc = q & 7; }
        const int ns = spatial ? NS_ : N_;
        const float* E    = spatial ? es : et;
        const float* Wemb = spatial ? W_se : W_te;
        const float* bemb = spatial ? b_se : b_te;
        const u16* Wf     = spatial ? Wf_s : Wf_t;
        const float* bs   = spatial ? bs_s : bs_t;
        u16* hb0 = spatial ? hsf0 : htf0;
        u16* hb1 = spatial ? hsf1 : htf1;

        const int wm = wid >> 1, wn = wid & 1;
        const int rb16 = rb * 8 + wm * 4;
        const int jb16 = jc * 8 + wn * 4;

        float biasv[4];
        #pragma unroll
        for (int g = 0; g < 4; ++g) biasv[g] = bs[jc * 128 + wn * 64 + g * 16 + l15];

        size_t ebase[4];
        #pragma unroll
        for (int mf = 0; mf < 4; ++mf) {
            int row = (rb16 + mf) * 16 + l15;
            int b = row / ns, s = row - b * ns;
            ebase[mf] = ((size_t)b * T_ * ns + s) * 2;
        }

        float creg[4][4];
        #pragma unroll
        for (int mf = 0; mf < 4; ++mf)
            #pragma unroll
            for (int r = 0; r < 4; ++r) creg[mf][r] = 0.f;

        const int cell = (jc * 2 + wn) * 16 + l15;
        const int rofs = (l >> 4) << 2;
        const int cpart = (cell >> 5) * 512 + ((cell >> 3) & 3) * 128 + (cell & 7);
        const int kemb0 = (l >> 4) * 8;

        for (int i = 0; i < T_; ++i) {
            const u16* Hf = (i & 1) ? hb1 : hb0;
            u16*       Hc = (i & 1) ? hb0 : hb1;

            float e0[4], e1[4];
            #pragma unroll
            for (int mf = 0; mf < 4; ++mf) {
                const float* ep = E + ebase[mf] + (size_t)i * ns * 2;
                e0[mf] = ep[0]; e1[mf] = ep[1];
            }

            f32x4 acc[4][4];
            #pragma unroll
            for (int mf = 0; mf < 4; ++mf)
                #pragma unroll
                for (int g = 0; g < 4; ++g)
                    acc[mf][g] = (f32x4){biasv[g], biasv[g], biasv[g], biasv[g]};

            #pragma unroll
            for (int kc = 0; kc < 12; ++kc) {
                bf16x8 a[4], b[4];
                if (kc < 4) {
                    #pragma unroll
                    for (int mf = 0; mf < 4; ++mf) {
                        u16x8 v;
                        #pragma unroll
                        for (int e = 0; e < 8; ++e) {
                            int k = kc * 32 + kemb0 + e;
                            float x = fmaf(e0[mf], Wemb[k * 2],
                                      fmaf(e1[mf], Wemb[k * 2 + 1], bemb[k]));
                            v[e] = f2bf(fmaxf(x, 0.f));
                        }
                        a[mf] = (bf16x8)v;
                    }
                } else {
                    #pragma unroll
                    for (int mf = 0; mf < 4; ++mf)
                        a[mf] = *(const bf16x8*)(Hf + (((size_t)(rb16 + mf)) * 8 + (kc - 4)) * 512 + lo8);
                }
                #pragma unroll
                for (int g = 0; g < 4; ++g)
                    b[g] = *(const bf16x8*)(Wf + (((size_t)(jb16 + g)) * 12 + kc) * 512 + lo8);
                #pragma unroll
                for (int mf = 0; mf < 4; ++mf)
                    #pragma unroll
                    for (int g = 0; g < 4; ++g)
                        acc[mf][g] = __builtin_amdgcn_mfma_f32_16x16x32_bf16(a[mf], b[g], acc[mf][g], 0, 0, 0);
            }

            #pragma unroll
            for (int mf = 0; mf < 4; ++mf) {
                #pragma unroll
                for (int r = 0; r < 4; ++r) {
                    float gi = acc[mf][0][r], gf = acc[mf][1][r];
                    float gg = acc[mf][2][r], go = acc[mf][3][r];
                    float c2 = sigm(gf) * creg[mf][r] + sigm(gi) * ftanh(gg);
                    creg[mf][r] = c2;
                    float h2 = sigm(go) * ftanh(c2);
                    Hc[(size_t)(rb16 + mf) * 4096 + cpart + (rofs + r) * 8] = f2bf(h2);
                }
            }
            gridbar(cnt, (unsigned)NBLK * (i + 1));
        }
        return;
    }

    // ===================== node + attn block =====================
    const int rb16n = blockIdx.x - 576;

    for (int x = tid; x < 4096; x += 256) hnfL[x] = 0;

    float cn[4][4];
    #pragma unroll
    for (int ch = 0; ch < 4; ++ch)
        #pragma unroll
        for (int r = 0; r < 4; ++r) cn[ch][r] = 0.f;

    const int rowN = rb16n * 16 + l15;
    const int bN = rowN / 12, nN = rowN - bN * 12;
    const size_t ninbase = ((size_t)bN * T_ * 12 + nN) * 2;
    const int kemb0 = (l >> 4) * 8;
    const int rofs = (l >> 4) << 2;

    __syncthreads();

    for (int i = 0; i <= T_; ++i) {
        if (i >= 1) {
            const int tn = i - 1;
            const u16* htfp = (i & 1) ? htf1 : htf0;
            const u16* hsfp = (i & 1) ? hsf1 : hsf0;

            {   // q = h_t @ Wq^T — one jb-tile per wave (was wave0-only)
                f32x4 qa = (f32x4){0.f, 0.f, 0.f, 0.f};
                #pragma unroll
                for (int kc = 0; kc < 8; ++kc) {
                    bf16x8 af = *(const bf16x8*)(htfp + ((size_t)rb16n * 8 + kc) * 512 + lo8);
                    bf16x8 bf = *(const bf16x8*)(Wqf + ((size_t)(wid * 8 + kc)) * 512 + lo8);
                    qa = __builtin_amdgcn_mfma_f32_16x16x32_bf16(af, bf, qa, 0, 0, 0);
                }
                int a = wid * 16 + l15;
                #pragma unroll
                for (int r = 0; r < 4; ++r)
                    q_lds[(l >> 4) * 4 + r][a] = qa[r] + bq[a];
            }
            __syncthreads();
            {   // qk = q @ Wk — 4 jb-tiles per wave (was wave0-only)
                f32x4 ka[4];
                #pragma unroll
                for (int j2 = 0; j2 < 4; ++j2) ka[j2] = (f32x4){0.f, 0.f, 0.f, 0.f};
                #pragma unroll
                for (int kc = 0; kc < 2; ++kc) {
                    int a0 = kc * 32 + (l >> 4) * 8;
                    bf16x8 af;
                    #pragma unroll
                    for (int e = 0; e < 8; ++e)
                        ((u16*)&af)[e] = f2bf(q_lds[l15][a0 + e]);
                    #pragma unroll
                    for (int j2 = 0; j2 < 4; ++j2) {
                        bf16x8 bf = *(const bf16x8*)(Wkqf + ((size_t)((wid * 4 + j2) * 2 + kc)) * 512 + lo8);
                        ka[j2] = __builtin_amdgcn_mfma_f32_16x16x32_bf16(af, bf, ka[j2], 0, 0, 0);
                    }
                }
                #pragma unroll
                for (int j2 = 0; j2 < 4; ++j2)
                    #pragma unroll
                    for (int r = 0; r < 4; ++r)
                        shbuf[(l >> 4) * 4 + r][(wid * 4 + j2) * 16 + l15] = ka[j2][r];
                if (tid < 16) {
                    float s = 0.f;
                    for (int a = 0; a < 64; ++a) s = fmaf(q_lds[tid][a], bk[a], s);
                    qb_lds[tid] = s;
                }
            }
            __syncthreads();
            if (tid < 176) {   // scores
                int row = tid / 11, kk = tid - row * 11;
                int r = rb16n * 16 + row;
                int srow = (r / 12) * 132 + (r % 12) * 11 + kk;
                float s = 0.f;
                #pragma unroll
                for (int k = 0; k < 256; k += 8) {
                    u16x8 v = *(const u16x8*)frag_row8(hsfp, srow, k, 8);
                    #pragma unroll
                    for (int e = 0; e < 8; ++e) s = fmaf(shbuf[row][k + e], bf2f(v[e]), s);
                }
                sc_lds[row][kk] = (s + qb_lds[row]) * TEMP_;
            }
            __syncthreads();
            if (tid < 16) {   // softmax over 11
                float m = sc_lds[tid][0];
                #pragma unroll
                for (int kk = 1; kk < 11; ++kk) m = fmaxf(m, sc_lds[tid][kk]);
                float ssum = 0.f;
                float wv[11];
                #pragma unroll
                for (int kk = 0; kk < 11; ++kk) { wv[kk] = __expf(sc_lds[tid][kk] - m); ssum += wv[kk]; }
                float inv = 1.f / ssum;
                #pragma unroll
                for (int kk = 0; kk < 11; ++kk) w_lds[tid][kk] = wv[kk] * inv;
            }
            __syncthreads();
            {   // h_attn -> shbuf
                int row = tid >> 4, c0 = (tid & 15) * 16;
                int r = rb16n * 16 + row;
                int sbase = (r / 12) * 132 + (r % 12) * 11;
                float hacc[16];
                #pragma unroll
                for (int e = 0; e < 16; ++e) hacc[e] = 0.f;
                #pragma unroll
                for (int kk = 0; kk < 11; ++kk) {
                    float wv = w_lds[row][kk];
                    int srow = sbase + kk;
                    u16x8 v0 = *(const u16x8*)frag_row8(hsfp, srow, c0, 8);
                    u16x8 v1 = *(const u16x8*)frag_row8(hsfp, srow, c0 + 8, 8);
                    #pragma unroll
                    for (int e = 0; e < 8; ++e) {
                        hacc[e]     = fmaf(wv, bf2f(v0[e]), hacc[e]);
                        hacc[8 + e] = fmaf(wv, bf2f(v1[e]), hacc[8 + e]);
                    }
                }
                #pragma unroll
                for (int e = 0; e < 16; ++e) shbuf[row][c0 + e] = hacc[e];
            }
            __syncthreads();
            {   // ein = [h_t | h_attn] @ W_edge^T -> einL
                f32x4 ea[2];
                ea[0] = (f32x4){0.f, 0.f, 0.f, 0.f};
                ea[1] = (f32x4){0.f, 0.f, 0.f, 0.f};
                #pragma unroll
                for (int kc = 0; kc < 16; ++kc) {
                    bf16x8 af;
                    if (kc < 8) {
                        af = *(const bf16x8*)(htfp + ((size_t)rb16n * 8 + kc) * 512 + lo8);
                    } else {
                        int k0 = (kc - 8) * 32 + (l >> 4) * 8;
                        #pragma unroll
                        for (int e = 0; e < 8; ++e)
                            ((u16*)&af)[e] = f2bf(shbuf[l15][k0 + e]);
                    }
                    #pragma unroll
                    for (int j2 = 0; j2 < 2; ++j2) {
                        bf16x8 bf = *(const bf16x8*)(Wef + ((size_t)((wid * 2 + j2) * 16 + kc)) * 512 + lo8);
                        ea[j2] = __builtin_amdgcn_mfma_f32_16x16x32_bf16(af, bf, ea[j2], 0, 0, 0);
                    }
                }
                #pragma unroll
                for (int j2 = 0; j2 < 2; ++j2) {
                    int cell = (wid * 2 + j2) * 16 + l15;
                    #pragma unroll
                    for (int r = 0; r < 4; ++r) {
                        int row = (l >> 4) * 4 + r;
                        float v = ea[j2][r] + b_edge[cell];
                        v = v > 0.f ? v : 0.f;
                        einL[(size_t)(cell >> 5) * 512 + (((cell >> 3) & 3) * 16 + row) * 8 + (cell & 7)] = f2bf(v);
                    }
                }
            }
            __syncthreads();
            {   // node LSTM GEMM (static acc indices)
                f32x4 na[4][4];
                #pragma unroll
                for (int ch = 0; ch < 4; ++ch)
                    #pragma unroll
                    for (int g = 0; g < 4; ++g) {
                        float bv = bs_n[(wid * 16 + ch * 4 + g) * 16 + l15];
                        na[ch][g] = (f32x4){bv, bv, bv, bv};
                    }
                #pragma unroll
                for (int kc = 0; kc < 16; ++kc) {
                    bf16x8 af;
                    if (kc < 4) {
                        const float* np = nodes + ninbase + (size_t)tn * 12 * 2;
                        float n0 = np[0], n1 = np[1];
                        u16x8 v;
                        #pragma unroll
                        for (int e = 0; e < 8; ++e) {
                            int k = kc * 32 + kemb0 + e;
                            float x = fmaf(n0, W_node[k * 2], fmaf(n1, W_node[k * 2 + 1], b_node[k]));
                            v[e] = f2bf(fmaxf(x, 0.f));
                        }
                        af = (bf16x8)v;
                    } else if (kc < 8) {
                        af = *(const bf16x8*)(einL + (size_t)(kc - 4) * 512 + lo8);
                    } else {
                        af = *(const bf16x8*)(hnfL + (size_t)(kc - 8) * 512 + lo8);
                    }
                    const u16* wb = Wf_n + (((size_t)(wid * 16)) * 16 + kc) * 512 + lo8;
                    #pragma unroll
                    for (int ch = 0; ch < 4; ++ch)
                        #pragma unroll
                        for (int g = 0; g < 4; ++g) {
                            bf16x8 bf = *(const bf16x8*)(wb + (size_t)(ch * 4 + g) * 16 * 512);
                            na[ch][g] = __builtin_amdgcn_mfma_f32_16x16x32_bf16(af, bf, na[ch][g], 0, 0, 0);
                        }
                }
                __syncthreads();   // done READING hnfL before overwrite
                u16* hist1 = hist + (size_t)i * 768 * 256;
                #pragma unroll
                for (int ch = 0; ch < 4; ++ch) {
                    int cell = (wid * 4 + ch) * 16 + l15;
                    int cpart = (cell >> 5) * 512 + ((cell >> 3) & 3) * 128 + (cell & 7);
                    #pragma unroll
                    for (int r = 0; r < 4; ++r) {
                        int rlow = rofs + r;
                        float gi = na[ch][0][r], gf = na[ch][1][r];
                        float gg = na[ch][2][r], go = na[ch][3][r];
                        float c2 = sigm(gf) * cn[ch][r] + sigm(gi) * ftanh(gg);
                        cn[ch][r] = c2;
                        float h2 = sigm(go) * ftanh(c2);
                        u16 hb = f2bf(h2);
                        hist1[((size_t)rb16n * 16 + rlow) * 256 + cell] = hb;
                        hnfL[cpart + rlow * 8] = hb;
                    }
                }
            }
        }
        if (i < T_) gridbar(cnt, (unsigned)NBLK * (i + 1));
    }
}

// out[b,t,n,q] = hist[t+1] . W_out^T + b_out
__global__ __launch_bounds__(256) void out_kernel(
    const u16* __restrict__ hist1, const float* __restrict__ W_out,
    const float* __restrict__ b_out, float* __restrict__ out)
{
    const int lane = threadIdx.x & 63;
    const int grp = threadIdx.x >> 6;
    for (int ridx = blockIdx.x * 4 + grp; ridx < 32 * 768; ridx += gridDim.x * 4) {
        int t = ridx / 768, row = ridx % 768;
        int b = row / 12, n = row % 12;
        const u16* h = &hist1[(size_t)ridx * 256];
        float hv[4];
        #pragma unroll
        for (int i = 0; i < 4; ++i) hv[i] = bf2f(h[i * 64 + lane]);
        #pragma unroll
        for (int q = 0; q < 5; ++q) {
            float s = 0.f;
            #pragma unroll
            for (int i = 0; i < 4; ++i) s = fmaf(hv[i], W_out[q * 256 + i * 64 + lane], s);
            #pragma unroll
            for (int off = 32; off > 0; off >>= 1) s += __shfl_down(s, off, 64);
            if (lane == 0)
                out[(((size_t)b * T_ + t) * N_ + n) * 5 + q] = s + b_out[q];
        }
    }
}

extern "C" void kernel_launch(void* const* d_in, const int* in_sizes, int n_in,
                              void* d_out, int out_size, void* d_ws, size_t ws_size,
                              hipStream_t stream)
{
    const float* nodes = (const float*)d_in[0];
    const float* et    = (const float*)d_in[1];
    const float* es    = (const float*)d_in[2];
    const float* W_te = (const float*)d_in[3];  const float* b_te = (const float*)d_in[4];
    const float* te_Wih = (const float*)d_in[5]; const float* te_Whh = (const float*)d_in[6];
    const float* te_bih = (const float*)d_in[7]; const float* te_bhh = (const float*)d_in[8];
    const float* W_se = (const float*)d_in[9];  const float* b_se = (const float*)d_in[10];
    const float* se_Wih = (const float*)d_in[11]; const float* se_Whh = (const float*)d_in[12];
    const float* se_bih = (const float*)d_in[13]; const float* se_bhh = (const float*)d_in[14];
    const float* Wq = (const float*)d_in[15]; const float* bq = (const float*)d_in[16];
    const float* Wk = (const float*)d_in[17]; const float* bk = (const float*)d_in[18];
    const float* W_node = (const float*)d_in[19]; const float* b_node = (const float*)d_in[20];
    const float* W_edge = (const float*)d_in[21]; const float* b_edge = (const float*)d_in[22];
    const float* nr_Wih = (const float*)d_in[23]; const float* nr_Whh = (const float*)d_in[24];
    const float* nr_bih = (const float*)d_in[25]; const float* nr_bhh = (const float*)d_in[26];
    const float* W_out = (const float*)d_in[27]; const float* b_out = (const float*)d_in[28];

    char* base = (char*)d_ws;
    size_t off = 0;
    auto A = [&](size_t bytes) { char* p = base + off; off += (bytes + 255) & ~(size_t)255; return p; };

    unsigned* cnt = (unsigned*)A(256);
    u16* htf0 = (u16*)A(768 * 256 * 2);
    u16* hsf0 = (u16*)A((size_t)8448 * 256 * 2);
    size_t zero_bytes = off;
    u16* htf1 = (u16*)A(768 * 256 * 2);
    u16* hsf1 = (u16*)A((size_t)8448 * 256 * 2);
    u16* hist = (u16*)A((size_t)33 * 768 * 256 * 2);
    u16* Wf_t = (u16*)A(1024 * 384 * 2);
    u16* Wf_s = (u16*)A(1024 * 384 * 2);
    u16* Wf_n = (u16*)A(1024 * 512 * 2);
    float* bs_t = (float*)A(1024 * 4);
    float* bs_s = (float*)A(1024 * 4);
    float* bs_n = (float*)A(1024 * 4);
    u16* Wqf  = (u16*)A(2048 * 8 * 2);
    u16* Wkqf = (u16*)A(2048 * 8 * 2);
    u16* Wef  = (u16*)A(8192 * 8 * 2);
    (void)ws_size;

    hipMemsetAsync(base, 0, zero_bytes, stream);

    prep_kernel<<<256, 256, 0, stream>>>(
        te_Wih, te_Whh, te_bih, te_bhh, se_Wih, se_Whh, se_bih, se_bhh,
        nr_Wih, nr_Whh, nr_bih, nr_bhh, Wq, Wk, W_edge,
        Wf_t, Wf_s, Wf_n, bs_t, bs_s, bs_n, Wqf, Wkqf, Wef);

    persist_kernel<<<NBLK, 256, 0, stream>>>(
        es, et, nodes,
        W_se, b_se, W_te, b_te, W_node, b_node,
        Wf_t, bs_t, Wf_s, bs_s, Wf_n, bs_n,
        htf0, htf1, hsf0, hsf1, hist,
        Wqf, bq, Wkqf, bk, Wef, b_edge, cnt);

    out_kernel<<<1536, 256, 0, stream>>>(hist + (size_t)768 * 256, W_out, b_out, (float*)d_out);
}

// Round 10
// 8422.210 us; speedup vs baseline: 7.3863x; 1.1304x over previous
//
#include <hip/hip_runtime.h>
#include <math.h>

#define B_ 64
#define T_ 32
#define N_ 12
#define NS_ 132
#define KN_ 11
#define TEMP_ 1.375f   // K_NEIGH / sqrt(ATTN) = 11/8
#define NBLK 624

typedef unsigned short u16;
typedef __attribute__((ext_vector_type(8))) short bf16x8;
typedef __attribute__((ext_vector_type(8))) unsigned short u16x8;
typedef __attribute__((ext_vector_type(4))) float f32x4;

__device__ __forceinline__ float sigm(float x) { return 1.f / (1.f + __expf(-x)); }
__device__ __forceinline__ float ftanh(float x) {
    float a = fabsf(x);
    float e = __expf(-2.f * a);
    float t = (1.f - e) / (1.f + e);
    return copysignf(t, x);
}
__device__ __forceinline__ u16 f2bf(float x) {
    union { float f; unsigned u; } v; v.f = x;
    unsigned r = v.u + 0x7fffu + ((v.u >> 16) & 1u);
    return (u16)(r >> 16);
}
__device__ __forceinline__ float bf2f(u16 h) {
    union { unsigned u; float f; } v; v.u = ((unsigned)h) << 16; return v.f;
}
__device__ __forceinline__ int origcol(int j) {
    return ((j >> 4) & 3) * 256 + ((j >> 6) << 4) + (j & 15);
}

// Fragment layout for M[R][K] (A/B operand of mfma 16x16x32 bf16):
//   tile = (r>>4)*(K/32) + (k>>5); lane = ((k>>3)&3)*16 + (r&15); elem = k&7
__device__ __forceinline__ const u16* frag_row8(const u16* basef, int row, int k, int nkc) {
    return basef + (((size_t)(row >> 4) * nkc + (k >> 5)) * 512)
                 + ((((k >> 3) & 3) * 16 + (row & 15)) * 8);
}

// Device-scope grid barrier, monotonic counter.
// RELEASE fetch_add flushes this block's dirty L2 lines (wbl2, keeps clean
// weight lines). RELAXED poll (r9-proven to see remote updates). NO acquire /
// __threadfence: r9's acquire-invalidate wiped every XCD L2 ~78x/iter
// (4.1 GB refetch). Correctness without acquire comes from WRITE-ONCE h
// buffers: no address is re-read after overwrite, so no cache can hold a
// stale copy of a line it will read.
__device__ __forceinline__ void gridbar(unsigned* cnt, unsigned target) {
    __syncthreads();
    if (threadIdx.x == 0) {
        __hip_atomic_fetch_add(cnt, 1u, __ATOMIC_RELEASE, __HIP_MEMORY_SCOPE_AGENT);
        while (__hip_atomic_load(cnt, __ATOMIC_RELAXED, __HIP_MEMORY_SCOPE_AGENT) < target)
            __builtin_amdgcn_s_sleep(8);
    }
    __syncthreads();
}

// ---------------------------------------------------------------------------
// prep: all weights -> bf16 fragment layout, fused biases.
// ---------------------------------------------------------------------------
__global__ __launch_bounds__(256) void prep_kernel(
    const float* __restrict__ te_Wih, const float* __restrict__ te_Whh,
    const float* __restrict__ te_bih, const float* __restrict__ te_bhh,
    const float* __restrict__ se_Wih, const float* __restrict__ se_Whh,
    const float* __restrict__ se_bih, const float* __restrict__ se_bhh,
    const float* __restrict__ nr_Wih, const float* __restrict__ nr_Whh,
    const float* __restrict__ nr_bih, const float* __restrict__ nr_bhh,
    const float* __restrict__ Wq, const float* __restrict__ Wk,
    const float* __restrict__ W_edge,
    u16* __restrict__ Wf_t, u16* __restrict__ Wf_s, u16* __restrict__ Wf_n,
    float* __restrict__ bs_t, float* __restrict__ bs_s, float* __restrict__ bs_n,
    u16* __restrict__ Wqf, u16* __restrict__ Wkqf, u16* __restrict__ Wef)
{
    int idx = blockIdx.x * 256 + threadIdx.x;
    if (idx < 49152) {
        int l = idx & 63, kc = (idx >> 6) % 12, jb16 = idx / 768;
        int j = jb16 * 16 + (l & 15);
        int c = origcol(j);
        int k0 = kc * 32 + (l >> 4) * 8;
        u16x8 vt, vs;
        #pragma unroll
        for (int i = 0; i < 8; ++i) {
            int k = k0 + i;
            vt[i] = f2bf((k < 128) ? te_Wih[c * 128 + k] : te_Whh[c * 256 + (k - 128)]);
            vs[i] = f2bf((k < 128) ? se_Wih[c * 128 + k] : se_Whh[c * 256 + (k - 128)]);
        }
        *(u16x8*)(Wf_t + (size_t)idx * 8) = vt;
        *(u16x8*)(Wf_s + (size_t)idx * 8) = vs;
    }
    if (idx < 65536) {
        int l = idx & 63, kc = (idx >> 6) & 15, jb16 = idx >> 10;
        int j = jb16 * 16 + (l & 15);
        int c = origcol(j);
        int k0 = kc * 32 + (l >> 4) * 8;
        u16x8 vn;
        #pragma unroll
        for (int i = 0; i < 8; ++i) {
            int k = k0 + i;
            vn[i] = f2bf((k < 256) ? nr_Wih[c * 256 + k] : nr_Whh[c * 256 + (k - 256)]);
        }
        *(u16x8*)(Wf_n + (size_t)idx * 8) = vn;
    }
    if (idx < 1024) {
        int c = origcol(idx);
        bs_t[idx] = te_bih[c] + te_bhh[c];
        bs_s[idx] = se_bih[c] + se_bhh[c];
        bs_n[idx] = nr_bih[c] + nr_bhh[c];
    }
    if (idx < 2048) {
        int l = idx & 63, tile = idx >> 6;
        int a = (tile >> 3) * 16 + (l & 15);
        int k0 = (tile & 7) * 32 + (l >> 4) * 8;
        u16x8 v;
        #pragma unroll
        for (int i = 0; i < 8; ++i) v[i] = f2bf(Wq[a * 256 + k0 + i]);
        *(u16x8*)(Wqf + (size_t)idx * 8) = v;
    }
    if (idx < 2048) {
        int l = idx & 63, tile = idx >> 6;
        int j = (tile >> 1) * 16 + (l & 15);
        int a0 = (tile & 1) * 32 + (l >> 4) * 8;
        u16x8 v;
        #pragma unroll
        for (int i = 0; i < 8; ++i) v[i] = f2bf(Wk[(a0 + i) * 256 + j]);
        *(u16x8*)(Wkqf + (size_t)idx * 8) = v;
    }
    if (idx < 8192) {
        int l = idx & 63, tile = idx >> 6;
        int c = (tile >> 4) * 16 + (l & 15);
        int k0 = (tile & 15) * 32 + (l >> 4) * 8;
        u16x8 v;
        #pragma unroll
        for (int i = 0; i < 8; ++i) v[i] = f2bf(W_edge[c * 512 + k0 + i]);
        *(u16x8*)(Wef + (size_t)idx * 8) = v;
    }
}

#define HT_SLOT (768 * 256)
#define HS_SLOT (8448 * 256)

// ---------------------------------------------------------------------------
// persist_kernel: entire T-step recurrence in one launch.
// blocks 0..527 spatial LSTM (XCD-chunked), 528..575 temporal LSTM,
// 576..623 attn + edge + node LSTM. Per iter i: lstm(i) || node(i-1).
// h states: 33 write-once slots (iter i reads slot i, writes slot i+1).
// ---------------------------------------------------------------------------
__global__ __launch_bounds__(256, 3) void persist_kernel(
    const float* __restrict__ es, const float* __restrict__ et,
    const float* __restrict__ nodes,
    const float* __restrict__ W_se, const float* __restrict__ b_se,
    const float* __restrict__ W_te, const float* __restrict__ b_te,
    const float* __restrict__ W_node, const float* __restrict__ b_node,
    const u16* __restrict__ Wf_t, const float* __restrict__ bs_t,
    const u16* __restrict__ Wf_s, const float* __restrict__ bs_s,
    const u16* __restrict__ Wf_n, const float* __restrict__ bs_n,
    u16* __restrict__ htf, u16* __restrict__ hsf,
    u16* __restrict__ hist,
    const u16* __restrict__ Wqf, const float* __restrict__ bq,
    const u16* __restrict__ Wkqf, const float* __restrict__ bk,
    const u16* __restrict__ Wef, const float* __restrict__ b_edge,
    unsigned* __restrict__ cnt)
{
    const int tid = threadIdx.x;
    const int l = tid & 63, l15 = l & 15;
    const size_t lo8 = (size_t)l * 8;
    const int wid = tid >> 6;

    __shared__ float q_lds[16][68];
    __shared__ float shbuf[16][260];
    __shared__ float sc_lds[16][12];
    __shared__ float w_lds[16][12];
    __shared__ float qb_lds[16];
    __shared__ u16 einL[2048];
    __shared__ u16 hnfL[4096];

    if ((int)blockIdx.x < 576) {
        // ===================== LSTM block =====================
        const int lb = blockIdx.x;
        const bool spatial = lb < 528;
        int rb, jc;
        if (spatial) { int orig = (lb & 7) * 66 + (lb >> 3); rb = orig >> 3; jc = orig & 7; }
        else         { int q = lb - 528;                      rb = q >> 3;    jc = q & 7; }
        const int ns = spatial ? NS_ : N_;
        const float* E    = spatial ? es : et;
        const float* Wemb = spatial ? W_se : W_te;
        const float* bemb = spatial ? b_se : b_te;
        const u16* Wf     = spatial ? Wf_s : Wf_t;
        const float* bs   = spatial ? bs_s : bs_t;
        u16* hbase = spatial ? hsf : htf;
        const size_t slot = spatial ? HS_SLOT : HT_SLOT;

        const int wm = wid >> 1, wn = wid & 1;
        const int rb16 = rb * 8 + wm * 4;
        const int jb16 = jc * 8 + wn * 4;

        float biasv[4];
        #pragma unroll
        for (int g = 0; g < 4; ++g) biasv[g] = bs[jc * 128 + wn * 64 + g * 16 + l15];

        size_t ebase[4];
        #pragma unroll
        for (int mf = 0; mf < 4; ++mf) {
            int row = (rb16 + mf) * 16 + l15;
            int b = row / ns, s = row - b * ns;
            ebase[mf] = ((size_t)b * T_ * ns + s) * 2;
        }

        float creg[4][4];
        #pragma unroll
        for (int mf = 0; mf < 4; ++mf)
            #pragma unroll
            for (int r = 0; r < 4; ++r) creg[mf][r] = 0.f;

        const int cell = (jc * 2 + wn) * 16 + l15;
        const int rofs = (l >> 4) << 2;
        const int cpart = (cell >> 5) * 512 + ((cell >> 3) & 3) * 128 + (cell & 7);
        const int kemb0 = (l >> 4) * 8;

        for (int i = 0; i < T_; ++i) {
            const u16* Hf = hbase + (size_t)i * slot;
            u16*       Hc = hbase + (size_t)(i + 1) * slot;

            float e0[4], e1[4];
            #pragma unroll
            for (int mf = 0; mf < 4; ++mf) {
                const float* ep = E + ebase[mf] + (size_t)i * ns * 2;
                e0[mf] = ep[0]; e1[mf] = ep[1];
            }

            f32x4 acc[4][4];
            #pragma unroll
            for (int mf = 0; mf < 4; ++mf)
                #pragma unroll
                for (int g = 0; g < 4; ++g)
                    acc[mf][g] = (f32x4){biasv[g], biasv[g], biasv[g], biasv[g]};

            #pragma unroll
            for (int kc = 0; kc < 12; ++kc) {
                bf16x8 a[4], b[4];
                if (kc < 4) {
                    #pragma unroll
                    for (int mf = 0; mf < 4; ++mf) {
                        u16x8 v;
                        #pragma unroll
                        for (int e = 0; e < 8; ++e) {
                            int k = kc * 32 + kemb0 + e;
                            float x = fmaf(e0[mf], Wemb[k * 2],
                                      fmaf(e1[mf], Wemb[k * 2 + 1], bemb[k]));
                            v[e] = f2bf(fmaxf(x, 0.f));
                        }
                        a[mf] = (bf16x8)v;
                    }
                } else {
                    #pragma unroll
                    for (int mf = 0; mf < 4; ++mf)
                        a[mf] = *(const bf16x8*)(Hf + (((size_t)(rb16 + mf)) * 8 + (kc - 4)) * 512 + lo8);
                }
                #pragma unroll
                for (int g = 0; g < 4; ++g)
                    b[g] = *(const bf16x8*)(Wf + (((size_t)(jb16 + g)) * 12 + kc) * 512 + lo8);
                #pragma unroll
                for (int mf = 0; mf < 4; ++mf)
                    #pragma unroll
                    for (int g = 0; g < 4; ++g)
                        acc[mf][g] = __builtin_amdgcn_mfma_f32_16x16x32_bf16(a[mf], b[g], acc[mf][g], 0, 0, 0);
            }

            #pragma unroll
            for (int mf = 0; mf < 4; ++mf) {
                #pragma unroll
                for (int r = 0; r < 4; ++r) {
                    float gi = acc[mf][0][r], gf = acc[mf][1][r];
                    float gg = acc[mf][2][r], go = acc[mf][3][r];
                    float c2 = sigm(gf) * creg[mf][r] + sigm(gi) * ftanh(gg);
                    creg[mf][r] = c2;
                    float h2 = sigm(go) * ftanh(c2);
                    Hc[(size_t)(rb16 + mf) * 4096 + cpart + (rofs + r) * 8] = f2bf(h2);
                }
            }
            gridbar(cnt, (unsigned)NBLK * (i + 1));
        }
        return;
    }

    // ===================== node + attn block =====================
    const int rb16n = blockIdx.x - 576;

    for (int x = tid; x < 4096; x += 256) hnfL[x] = 0;

    float cn[4][4];
    #pragma unroll
    for (int ch = 0; ch < 4; ++ch)
        #pragma unroll
        for (int r = 0; r < 4; ++r) cn[ch][r] = 0.f;

    const int rowN = rb16n * 16 + l15;
    const int bN = rowN / 12, nN = rowN - bN * 12;
    const size_t ninbase = ((size_t)bN * T_ * 12 + nN) * 2;
    const int kemb0 = (l >> 4) * 8;
    const int rofs = (l >> 4) << 2;

    __syncthreads();

    for (int i = 0; i <= T_; ++i) {
        if (i >= 1) {
            const int tn = i - 1;
            const u16* htfp = htf + (size_t)i * HT_SLOT;
            const u16* hsfp = hsf + (size_t)i * HS_SLOT;

            {   // q = h_t @ Wq^T — one jb-tile per wave
                f32x4 qa = (f32x4){0.f, 0.f, 0.f, 0.f};
                #pragma unroll
                for (int kc = 0; kc < 8; ++kc) {
                    bf16x8 af = *(const bf16x8*)(htfp + ((size_t)rb16n * 8 + kc) * 512 + lo8);
                    bf16x8 bf = *(const bf16x8*)(Wqf + ((size_t)(wid * 8 + kc)) * 512 + lo8);
                    qa = __builtin_amdgcn_mfma_f32_16x16x32_bf16(af, bf, qa, 0, 0, 0);
                }
                int a = wid * 16 + l15;
                #pragma unroll
                for (int r = 0; r < 4; ++r)
                    q_lds[(l >> 4) * 4 + r][a] = qa[r] + bq[a];
            }
            __syncthreads();
            {   // qk = q @ Wk — 4 jb-tiles per wave
                f32x4 ka[4];
                #pragma unroll
                for (int j2 = 0; j2 < 4; ++j2) ka[j2] = (f32x4){0.f, 0.f, 0.f, 0.f};
                #pragma unroll
                for (int kc = 0; kc < 2; ++kc) {
                    int a0 = kc * 32 + (l >> 4) * 8;
                    bf16x8 af;
                    #pragma unroll
                    for (int e = 0; e < 8; ++e)
                        ((u16*)&af)[e] = f2bf(q_lds[l15][a0 + e]);
                    #pragma unroll
                    for (int j2 = 0; j2 < 4; ++j2) {
                        bf16x8 bf = *(const bf16x8*)(Wkqf + ((size_t)((wid * 4 + j2) * 2 + kc)) * 512 + lo8);
                        ka[j2] = __builtin_amdgcn_mfma_f32_16x16x32_bf16(af, bf, ka[j2], 0, 0, 0);
                    }
                }
                #pragma unroll
                for (int j2 = 0; j2 < 4; ++j2)
                    #pragma unroll
                    for (int r = 0; r < 4; ++r)
                        shbuf[(l >> 4) * 4 + r][(wid * 4 + j2) * 16 + l15] = ka[j2][r];
                if (tid < 16) {
                    float s = 0.f;
                    for (int a = 0; a < 64; ++a) s = fmaf(q_lds[tid][a], bk[a], s);
                    qb_lds[tid] = s;
                }
            }
            __syncthreads();
            if (tid < 176) {   // scores
                int row = tid / 11, kk = tid - row * 11;
                int r = rb16n * 16 + row;
                int srow = (r / 12) * 132 + (r % 12) * 11 + kk;
                float s = 0.f;
                #pragma unroll
                for (int k = 0; k < 256; k += 8) {
                    u16x8 v = *(const u16x8*)frag_row8(hsfp, srow, k, 8);
                    #pragma unroll
                    for (int e = 0; e < 8; ++e) s = fmaf(shbuf[row][k + e], bf2f(v[e]), s);
                }
                sc_lds[row][kk] = (s + qb_lds[row]) * TEMP_;
            }
            __syncthreads();
            if (tid < 16) {   // softmax over 11
                float m = sc_lds[tid][0];
                #pragma unroll
                for (int kk = 1; kk < 11; ++kk) m = fmaxf(m, sc_lds[tid][kk]);
                float ssum = 0.f;
                float wv[11];
                #pragma unroll
                for (int kk = 0; kk < 11; ++kk) { wv[kk] = __expf(sc_lds[tid][kk] - m); ssum += wv[kk]; }
                float inv = 1.f / ssum;
                #pragma unroll
                for (int kk = 0; kk < 11; ++kk) w_lds[tid][kk] = wv[kk] * inv;
            }
            __syncthreads();
            {   // h_attn -> shbuf
                int row = tid >> 4, c0 = (tid & 15) * 16;
                int r = rb16n * 16 + row;
                int sbase = (r / 12) * 132 + (r % 12) * 11;
                float hacc[16];
                #pragma unroll
                for (int e = 0; e < 16; ++e) hacc[e] = 0.f;
                #pragma unroll
                for (int kk = 0; kk < 11; ++kk) {
                    float wv = w_lds[row][kk];
                    int srow = sbase + kk;
                    u16x8 v0 = *(const u16x8*)frag_row8(hsfp, srow, c0, 8);
                    u16x8 v1 = *(const u16x8*)frag_row8(hsfp, srow, c0 + 8, 8);
                    #pragma unroll
                    for (int e = 0; e < 8; ++e) {
                        hacc[e]     = fmaf(wv, bf2f(v0[e]), hacc[e]);
                        hacc[8 + e] = fmaf(wv, bf2f(v1[e]), hacc[8 + e]);
                    }
                }
                #pragma unroll
                for (int e = 0; e < 16; ++e) shbuf[row][c0 + e] = hacc[e];
            }
            __syncthreads();
            {   // ein = [h_t | h_attn] @ W_edge^T -> einL
                f32x4 ea[2];
                ea[0] = (f32x4){0.f, 0.f, 0.f, 0.f};
                ea[1] = (f32x4){0.f, 0.f, 0.f, 0.f};
                #pragma unroll
                for (int kc = 0; kc < 16; ++kc) {
                    bf16x8 af;
                    if (kc < 8) {
                        af = *(const bf16x8*)(htfp + ((size_t)rb16n * 8 + kc) * 512 + lo8);
                    } else {
                        int k0 = (kc - 8) * 32 + (l >> 4) * 8;
                        #pragma unroll
                        for (int e = 0; e < 8; ++e)
                            ((u16*)&af)[e] = f2bf(shbuf[l15][k0 + e]);
                    }
                    #pragma unroll
                    for (int j2 = 0; j2 < 2; ++j2) {
                        bf16x8 bf = *(const bf16x8*)(Wef + ((size_t)((wid * 2 + j2) * 16 + kc)) * 512 + lo8);
                        ea[j2] = __builtin_amdgcn_mfma_f32_16x16x32_bf16(af, bf, ea[j2], 0, 0, 0);
                    }
                }
                #pragma unroll
                for (int j2 = 0; j2 < 2; ++j2) {
                    int cell = (wid * 2 + j2) * 16 + l15;
                    #pragma unroll
                    for (int r = 0; r < 4; ++r) {
                        int row = (l >> 4) * 4 + r;
                        float v = ea[j2][r] + b_edge[cell];
                        v = v > 0.f ? v : 0.f;
                        einL[(size_t)(cell >> 5) * 512 + (((cell >> 3) & 3) * 16 + row) * 8 + (cell & 7)] = f2bf(v);
                    }
                }
            }
            __syncthreads();
            {   // node LSTM GEMM (static acc indices)
                f32x4 na[4][4];
                #pragma unroll
                for (int ch = 0; ch < 4; ++ch)
                    #pragma unroll
                    for (int g = 0; g < 4; ++g) {
                        float bv = bs_n[(wid * 16 + ch * 4 + g) * 16 + l15];
                        na[ch][g] = (f32x4){bv, bv, bv, bv};
                    }
                #pragma unroll
                for (int kc = 0; kc < 16; ++kc) {
                    bf16x8 af;
                    if (kc < 4) {
                        const float* np = nodes + ninbase + (size_t)tn * 12 * 2;
                        float n0 = np[0], n1 = np[1];
                        u16x8 v;
                        #pragma unroll
                        for (int e = 0; e < 8; ++e) {
                            int k = kc * 32 + kemb0 + e;
                            float x = fmaf(n0, W_node[k * 2], fmaf(n1, W_node[k * 2 + 1], b_node[k]));
                            v[e] = f2bf(fmaxf(x, 0.f));
                        }
                        af = (bf16x8)v;
                    } else if (kc < 8) {
                        af = *(const bf16x8*)(einL + (size_t)(kc - 4) * 512 + lo8);
                    } else {
                        af = *(const bf16x8*)(hnfL + (size_t)(kc - 8) * 512 + lo8);
                    }
                    const u16* wb = Wf_n + (((size_t)(wid * 16)) * 16 + kc) * 512 + lo8;
                    #pragma unroll
                    for (int ch = 0; ch < 4; ++ch)
                        #pragma unroll
                        for (int g = 0; g < 4; ++g) {
                            bf16x8 bf = *(const bf16x8*)(wb + (size_t)(ch * 4 + g) * 16 * 512);
                            na[ch][g] = __builtin_amdgcn_mfma_f32_16x16x32_bf16(af, bf, na[ch][g], 0, 0, 0);
                        }
                }
                __syncthreads();   // done READING hnfL before overwrite
                u16* hist1 = hist + (size_t)i * 768 * 256;
                #pragma unroll
                for (int ch = 0; ch < 4; ++ch) {
                    int cell = (wid * 4 + ch) * 16 + l15;
                    int cpart = (cell >> 5) * 512 + ((cell >> 3) & 3) * 128 + (cell & 7);
                    #pragma unroll
                    for (int r = 0; r < 4; ++r) {
                        int rlow = rofs + r;
                        float gi = na[ch][0][r], gf = na[ch][1][r];
                        float gg = na[ch][2][r], go = na[ch][3][r];
                        float c2 = sigm(gf) * cn[ch][r] + sigm(gi) * ftanh(gg);
                        cn[ch][r] = c2;
                        float h2 = sigm(go) * ftanh(c2);
                        u16 hb = f2bf(h2);
                        hist1[((size_t)rb16n * 16 + rlow) * 256 + cell] = hb;
                        hnfL[cpart + rlow * 8] = hb;
                    }
                }
            }
        }
        if (i < T_) gridbar(cnt, (unsigned)NBLK * (i + 1));
    }
}

// out[b,t,n,q] = hist[t+1] . W_out^T + b_out
__global__ __launch_bounds__(256) void out_kernel(
    const u16* __restrict__ hist1, const float* __restrict__ W_out,
    const float* __restrict__ b_out, float* __restrict__ out)
{
    const int lane = threadIdx.x & 63;
    const int grp = threadIdx.x >> 6;
    for (int ridx = blockIdx.x * 4 + grp; ridx < 32 * 768; ridx += gridDim.x * 4) {
        int t = ridx / 768, row = ridx % 768;
        int b = row / 12, n = row % 12;
        const u16* h = &hist1[(size_t)ridx * 256];
        float hv[4];
        #pragma unroll
        for (int i = 0; i < 4; ++i) hv[i] = bf2f(h[i * 64 + lane]);
        #pragma unroll
        for (int q = 0; q < 5; ++q) {
            float s = 0.f;
            #pragma unroll
            for (int i = 0; i < 4; ++i) s = fmaf(hv[i], W_out[q * 256 + i * 64 + lane], s);
            #pragma unroll
            for (int off = 32; off > 0; off >>= 1) s += __shfl_down(s, off, 64);
            if (lane == 0)
                out[(((size_t)b * T_ + t) * N_ + n) * 5 + q] = s + b_out[q];
        }
    }
}

extern "C" void kernel_launch(void* const* d_in, const int* in_sizes, int n_in,
                              void* d_out, int out_size, void* d_ws, size_t ws_size,
                              hipStream_t stream)
{
    const float* nodes = (const float*)d_in[0];
    const float* et    = (const float*)d_in[1];
    const float* es    = (const float*)d_in[2];
    const float* W_te = (const float*)d_in[3];  const float* b_te = (const float*)d_in[4];
    const float* te_Wih = (const float*)d_in[5]; const float* te_Whh = (const float*)d_in[6];
    const float* te_bih = (const float*)d_in[7]; const float* te_bhh = (const float*)d_in[8];
    const float* W_se = (const float*)d_in[9];  const float* b_se = (const float*)d_in[10];
    const float* se_Wih = (const float*)d_in[11]; const float* se_Whh = (const float*)d_in[12];
    const float* se_bih = (const float*)d_in[13]; const float* se_bhh = (const float*)d_in[14];
    const float* Wq = (const float*)d_in[15]; const float* bq = (const float*)d_in[16];
    const float* Wk = (const float*)d_in[17]; const float* bk = (const float*)d_in[18];
    const float* W_node = (const float*)d_in[19]; const float* b_node = (const float*)d_in[20];
    const float* W_edge = (const float*)d_in[21]; const float* b_edge = (const float*)d_in[22];
    const float* nr_Wih = (const float*)d_in[23]; const float* nr_Whh = (const float*)d_in[24];
    const float* nr_bih = (const float*)d_in[25]; const float* nr_bhh = (const float*)d_in[26];
    const float* W_out = (const float*)d_in[27]; const float* b_out = (const float*)d_in[28];

    char* base = (char*)d_ws;
    size_t off = 0;
    auto A = [&](size_t bytes) { char* p = base + off; off += (bytes + 255) & ~(size_t)255; return p; };

    unsigned* cnt = (unsigned*)A(256);
    u16* htf = (u16*)A((size_t)33 * HT_SLOT * 2);   // 33 write-once slots
    u16* hsf = (u16*)A((size_t)33 * HS_SLOT * 2);
    u16* hist = (u16*)A((size_t)33 * 768 * 256 * 2);
    u16* Wf_t = (u16*)A(1024 * 384 * 2);
    u16* Wf_s = (u16*)A(1024 * 384 * 2);
    u16* Wf_n = (u16*)A(1024 * 512 * 2);
    float* bs_t = (float*)A(1024 * 4);
    float* bs_s = (float*)A(1024 * 4);
    float* bs_n = (float*)A(1024 * 4);
    u16* Wqf  = (u16*)A(2048 * 8 * 2);
    u16* Wkqf = (u16*)A(2048 * 8 * 2);
    u16* Wef  = (u16*)A(8192 * 8 * 2);
    (void)ws_size;

    // zero: counter + h slot 0 (h(0) = 0)
    hipMemsetAsync(cnt, 0, 256, stream);
    hipMemsetAsync(htf, 0, (size_t)HT_SLOT * 2, stream);
    hipMemsetAsync(hsf, 0, (size_t)HS_SLOT * 2, stream);

    prep_kernel<<<256, 256, 0, stream>>>(
        te_Wih, te_Whh, te_bih, te_bhh, se_Wih, se_Whh, se_bih, se_bhh,
        nr_Wih, nr_Whh, nr_bih, nr_bhh, Wq, Wk, W_edge,
        Wf_t, Wf_s, Wf_n, bs_t, bs_s, bs_n, Wqf, Wkqf, Wef);

    persist_kernel<<<NBLK, 256, 0, stream>>>(
        es, et, nodes,
        W_se, b_se, W_te, b_te, W_node, b_node,
        Wf_t, bs_t, Wf_s, bs_s, Wf_n, bs_n,
        htf, hsf, hist,
        Wqf, bq, Wkqf, bk, Wef, b_edge, cnt);

    out_kernel<<<1536, 256, 0, stream>>>(hist + (size_t)768 * 256, W_out, b_out, (float*)d_out);
}

// Round 11
// 1057.788 us; speedup vs baseline: 58.8106x; 7.9621x over previous
//
#include <hip/hip_runtime.h>
#include <math.h>

#define B_ 64
#define T_ 32
#define N_ 12
#define NS_ 132
#define KN_ 11
#define TEMP_ 1.375f   // K_NEIGH / sqrt(ATTN) = 11/8

typedef unsigned short u16;
typedef __attribute__((ext_vector_type(8))) short bf16x8;
typedef __attribute__((ext_vector_type(8))) unsigned short u16x8;
typedef __attribute__((ext_vector_type(4))) float f32x4;

__device__ __forceinline__ float sigm(float x) { return 1.f / (1.f + __expf(-x)); }
__device__ __forceinline__ float ftanh(float x) {
    float a = fabsf(x);
    float e = __expf(-2.f * a);
    float t = (1.f - e) / (1.f + e);
    return copysignf(t, x);
}
__device__ __forceinline__ u16 f2bf(float x) {
    union { float f; unsigned u; } v; v.f = x;
    unsigned r = v.u + 0x7fffu + ((v.u >> 16) & 1u);
    return (u16)(r >> 16);
}
__device__ __forceinline__ float bf2f(u16 h) {
    union { unsigned u; float f; } v; v.u = ((unsigned)h) << 16; return v.f;
}
__device__ __forceinline__ int origcol(int j) {
    return ((j >> 4) & 3) * 256 + ((j >> 6) << 4) + (j & 15);
}

// Fragment layout for M[R][K] (A/B operand of mfma 16x16x32 bf16):
//   tile = (r>>4)*(K/32) + (k>>5); lane = ((k>>3)&3)*16 + (r&15); elem = k&7
//   flat u16 index = tile*512 + lane*8 + elem

// ---------------------------------------------------------------------------
// prep: all weights -> bf16 fragment layout, fused biases.
// ---------------------------------------------------------------------------
__global__ __launch_bounds__(256) void prep_kernel(
    const float* __restrict__ te_Wih, const float* __restrict__ te_Whh,
    const float* __restrict__ te_bih, const float* __restrict__ te_bhh,
    const float* __restrict__ se_Wih, const float* __restrict__ se_Whh,
    const float* __restrict__ se_bih, const float* __restrict__ se_bhh,
    const float* __restrict__ nr_Wih, const float* __restrict__ nr_Whh,
    const float* __restrict__ nr_bih, const float* __restrict__ nr_bhh,
    const float* __restrict__ Wq, const float* __restrict__ Wk,
    const float* __restrict__ W_edge,
    u16* __restrict__ Wf_t, u16* __restrict__ Wf_s, u16* __restrict__ Wf_n,
    float* __restrict__ bs_t, float* __restrict__ bs_s, float* __restrict__ bs_n,
    u16* __restrict__ Wqf, u16* __restrict__ Wkqf, u16* __restrict__ Wef)
{
    int idx = blockIdx.x * 256 + threadIdx.x;
    if (idx < 49152) {
        int l = idx & 63, kc = (idx >> 6) % 12, jb16 = idx / 768;
        int j = jb16 * 16 + (l & 15);
        int c = origcol(j);
        int k0 = kc * 32 + (l >> 4) * 8;
        u16x8 vt, vs;
        #pragma unroll
        for (int i = 0; i < 8; ++i) {
            int k = k0 + i;
            vt[i] = f2bf((k < 128) ? te_Wih[c * 128 + k] : te_Whh[c * 256 + (k - 128)]);
            vs[i] = f2bf((k < 128) ? se_Wih[c * 128 + k] : se_Whh[c * 256 + (k - 128)]);
        }
        *(u16x8*)(Wf_t + (size_t)idx * 8) = vt;
        *(u16x8*)(Wf_s + (size_t)idx * 8) = vs;
    }
    if (idx < 65536) {
        int l = idx & 63, kc = (idx >> 6) & 15, jb16 = idx >> 10;
        int j = jb16 * 16 + (l & 15);
        int c = origcol(j);
        int k0 = kc * 32 + (l >> 4) * 8;
        u16x8 vn;
        #pragma unroll
        for (int i = 0; i < 8; ++i) {
            int k = k0 + i;
            vn[i] = f2bf((k < 256) ? nr_Wih[c * 256 + k] : nr_Whh[c * 256 + (k - 256)]);
        }
        *(u16x8*)(Wf_n + (size_t)idx * 8) = vn;
    }
    if (idx < 1024) {
        int c = origcol(idx);
        bs_t[idx] = te_bih[c] + te_bhh[c];
        bs_s[idx] = se_bih[c] + se_bhh[c];
        bs_n[idx] = nr_bih[c] + nr_bhh[c];
    }
    if (idx < 2048) {
        int l = idx & 63, tile = idx >> 6;
        int a = (tile >> 3) * 16 + (l & 15);
        int k0 = (tile & 7) * 32 + (l >> 4) * 8;
        u16x8 v;
        #pragma unroll
        for (int i = 0; i < 8; ++i) v[i] = f2bf(Wq[a * 256 + k0 + i]);
        *(u16x8*)(Wqf + (size_t)idx * 8) = v;
    }
    if (idx < 2048) {
        int l = idx & 63, tile = idx >> 6;
        int j = (tile >> 1) * 16 + (l & 15);
        int a0 = (tile & 1) * 32 + (l >> 4) * 8;
        u16x8 v;
        #pragma unroll
        for (int i = 0; i < 8; ++i) v[i] = f2bf(Wk[(a0 + i) * 256 + j]);
        *(u16x8*)(Wkqf + (size_t)idx * 8) = v;
    }
    if (idx < 8192) {
        int l = idx & 63, tile = idx >> 6;
        int c = (tile >> 4) * 16 + (l & 15);
        int k0 = (tile & 15) * 32 + (l >> 4) * 8;
        u16x8 v;
        #pragma unroll
        for (int i = 0; i < 8; ++i) v[i] = f2bf(W_edge[c * 512 + k0 + i]);
        *(u16x8*)(Wef + (size_t)idx * 8) = v;
    }
}

// nin embeddings in fragment layout: u = ((t*48+rb16)*4+kc)*64 + l
__global__ __launch_bounds__(256) void emb_nin_kernel(
    const float* __restrict__ nodes,
    const float* __restrict__ W_node, const float* __restrict__ b_node,
    u16* __restrict__ ninf)
{
    int u = blockIdx.x * 256 + threadIdx.x;   // 32*48*4*64 = 393216 exact
    int l = u & 63, kc = (u >> 6) & 3;
    int rt = u >> 8;
    int rb16 = rt % 48, t = rt / 48;
    int row = rb16 * 16 + (l & 15);
    int b = row / 12, n = row - b * 12;
    size_t src = (((size_t)b * T_ + t) * N_ + n) * 2;
    float n0 = nodes[src], n1 = nodes[src + 1];
    int k0 = kc * 32 + (l >> 4) * 8;
    u16x8 vn;
    #pragma unroll
    for (int i = 0; i < 8; ++i) {
        int k = k0 + i;
        float y = fmaf(n0, W_node[k * 2], fmaf(n1, W_node[k * 2 + 1], b_node[k]));
        vn[i] = f2bf(fmaxf(y, 0.f));
    }
    *(u16x8*)(ninf + (size_t)u * 8) = vn;
}

// ---------------------------------------------------------------------------
// step_kernel — three independent block ranges, ONE dispatch per timestep:
//   [0, nA)          : attention + edge-input for step t  (48 blocks)
//   [nA, nA+nN)      : node LSTM for step t-1             (192 blocks)
//   [nA+nN, +576)    : temporal+spatial LSTM for step t+1 (576 blocks, M=128,
//                      embeddings computed inline from es/et)
// All ranges only read buffers written by PREVIOUS dispatches (ping-pong by
// parity); no intra-dispatch cross-range dependencies.
// ---------------------------------------------------------------------------
__global__ __launch_bounds__(256) void step_kernel(
    int nA, int nN, int iL,
    const float* __restrict__ es, const float* __restrict__ et,
    const float* __restrict__ W_se, const float* __restrict__ b_se,
    const float* __restrict__ W_te, const float* __restrict__ b_te,
    const u16* __restrict__ Wf_t, const float* __restrict__ bs_t,
    const u16* __restrict__ Wf_s, const float* __restrict__ bs_s,
    const u16* __restrict__ L_htp, u16* __restrict__ L_htc, float* __restrict__ c_t,
    const u16* __restrict__ L_hsp, u16* __restrict__ L_hsc,
    u16* __restrict__ L_hsd_w, float* __restrict__ c_s,
    const u16* __restrict__ A_htf, const u16* __restrict__ A_hsd,
    u16* __restrict__ A_ein,
    const u16* __restrict__ Wqf, const float* __restrict__ bq,
    const u16* __restrict__ Wkqf, const float* __restrict__ bk,
    const u16* __restrict__ Wef, const float* __restrict__ b_edge,
    const u16* __restrict__ ninf_m, const u16* __restrict__ N_ein,
    const u16* __restrict__ Wf_n, const float* __restrict__ bs_n,
    const u16* __restrict__ N_hnp, u16* __restrict__ N_hnc,
    u16* __restrict__ hist1, float* __restrict__ c_n)
{
    const int tid = threadIdx.x;
    const int l = tid & 63, l15 = l & 15;
    const size_t lo8 = (size_t)l * 8;
    const int wid = tid >> 6;

    if ((int)blockIdx.x >= nA + nN) {
        // ================= temporal+spatial LSTM (step iL, M=128) =================
        const int lb = blockIdx.x - nA - nN;
        const bool spatial = lb < 528;
        int rb, jc;
        if (spatial) { int orig = (lb & 7) * 66 + (lb >> 3); rb = orig >> 3; jc = orig & 7; }
        else         { int q = lb - 528;                      rb = q >> 3;    jc = q & 7; }
        const int ns = spatial ? NS_ : N_;
        const float* E    = spatial ? es : et;
        const float* Wemb = spatial ? W_se : W_te;
        const float* bemb = spatial ? b_se : b_te;
        const u16* Wf     = spatial ? Wf_s : Wf_t;
        const float* bs   = spatial ? bs_s : bs_t;
        const u16* Hf = spatial ? L_hsp : L_htp;
        u16*       Hc = spatial ? L_hsc : L_htc;
        float* C  = spatial ? c_s : c_t;

        const int wm = wid >> 1, wn = wid & 1;
        const int rb16 = rb * 8 + wm * 4;
        const int jb16 = jc * 8 + wn * 4;
        const int kemb0 = (l >> 4) * 8;

        float biasv[4];
        #pragma unroll
        for (int g = 0; g < 4; ++g) biasv[g] = bs[jc * 128 + wn * 64 + g * 16 + l15];

        float e0[4], e1[4];
        #pragma unroll
        for (int mf = 0; mf < 4; ++mf) {
            int row = (rb16 + mf) * 16 + l15;
            int b = row / ns, s = row - b * ns;
            const float* ep = E + (((size_t)b * T_ + iL) * ns + s) * 2;
            e0[mf] = ep[0]; e1[mf] = ep[1];
        }

        f32x4 acc[4][4];
        #pragma unroll
        for (int mf = 0; mf < 4; ++mf)
            #pragma unroll
            for (int g = 0; g < 4; ++g)
                acc[mf][g] = (f32x4){biasv[g], biasv[g], biasv[g], biasv[g]};

        #pragma unroll
        for (int kc = 0; kc < 12; ++kc) {
            bf16x8 a[4], b[4];
            if (kc < 4) {   // embedding frags computed inline
                #pragma unroll
                for (int mf = 0; mf < 4; ++mf) {
                    u16x8 v;
                    #pragma unroll
                    for (int e = 0; e < 8; ++e) {
                        int k = kc * 32 + kemb0 + e;
                        float x = fmaf(e0[mf], Wemb[k * 2],
                                  fmaf(e1[mf], Wemb[k * 2 + 1], bemb[k]));
                        v[e] = f2bf(fmaxf(x, 0.f));
                    }
                    a[mf] = (bf16x8)v;
                }
            } else {
                #pragma unroll
                for (int mf = 0; mf < 4; ++mf)
                    a[mf] = *(const bf16x8*)(Hf + (((size_t)(rb16 + mf)) * 8 + (kc - 4)) * 512 + lo8);
            }
            #pragma unroll
            for (int g = 0; g < 4; ++g)
                b[g] = *(const bf16x8*)(Wf + (((size_t)(jb16 + g)) * 12 + kc) * 512 + lo8);
            #pragma unroll
            for (int mf = 0; mf < 4; ++mf)
                #pragma unroll
                for (int g = 0; g < 4; ++g)
                    acc[mf][g] = __builtin_amdgcn_mfma_f32_16x16x32_bf16(a[mf], b[g], acc[mf][g], 0, 0, 0);
        }

        const int cell = (jc * 2 + wn) * 16 + l15;
        const int rofs = (l >> 4) << 2;
        const int cpart = (cell >> 5) * 512 + ((cell >> 3) & 3) * 128 + (cell & 7);
        #pragma unroll
        for (int mf = 0; mf < 4; ++mf) {
            int r16 = rb16 + mf;
            #pragma unroll
            for (int r = 0; r < 4; ++r) {
                int rlow = rofs + r;
                size_t doff = ((size_t)r16 * 16 + rlow) * 256 + cell;
                float gi = acc[mf][0][r], gf = acc[mf][1][r];
                float gg = acc[mf][2][r], go = acc[mf][3][r];
                float c2 = sigm(gf) * C[doff] + sigm(gi) * ftanh(gg);
                float h2 = sigm(go) * ftanh(c2);
                C[doff] = c2;
                u16 hb = f2bf(h2);
                if (spatial) L_hsd_w[doff] = hb;
                Hc[(size_t)r16 * 4096 + cpart + rlow * 8] = hb;
            }
        }
        return;
    }

    if ((int)blockIdx.x >= nA) {
        // ================= node LSTM (step m, 192 blocks) =================
        const int nb = blockIdx.x - nA;
        const int rb16 = nb >> 2, jq = nb & 3;
        const int wn = wid;

        f32x4 acc[4];
        #pragma unroll
        for (int g = 0; g < 4; ++g) {
            float bv = bs_n[jq * 256 + wn * 64 + g * 16 + l15];
            acc[g] = (f32x4){bv, bv, bv, bv};
        }
        #pragma unroll
        for (int kc = 0; kc < 16; ++kc) {
            const u16* p;
            if (kc < 4)       p = ninf_m + ((size_t)rb16 * 4 + kc) * 512 + lo8;
            else if (kc < 8)  p = N_ein  + ((size_t)rb16 * 4 + (kc - 4)) * 512 + lo8;
            else              p = N_hnp  + ((size_t)rb16 * 8 + (kc - 8)) * 512 + lo8;
            bf16x8 af = *(const bf16x8*)p;
            #pragma unroll
            for (int g = 0; g < 4; ++g) {
                bf16x8 bf = *(const bf16x8*)(Wf_n + (((size_t)(jq * 16 + wn * 4 + g)) * 16 + kc) * 512 + lo8);
                acc[g] = __builtin_amdgcn_mfma_f32_16x16x32_bf16(af, bf, acc[g], 0, 0, 0);
            }
        }
        const int cell = (jq * 4 + wn) * 16 + l15;
        const int rofs = (l >> 4) << 2;
        const int cpart = (cell >> 5) * 512 + ((cell >> 3) & 3) * 128 + (cell & 7);
        #pragma unroll
        for (int r = 0; r < 4; ++r) {
            int rlow = rofs + r;
            size_t doff = ((size_t)rb16 * 16 + rlow) * 256 + cell;
            float gi = acc[0][r], gf = acc[1][r], gg = acc[2][r], go = acc[3][r];
            float c2 = sigm(gf) * c_n[doff] + sigm(gi) * ftanh(gg);
            float h2 = sigm(go) * ftanh(c2);
            c_n[doff] = c2;
            u16 hb = f2bf(h2);
            hist1[doff] = hb;
            N_hnc[(size_t)rb16 * 4096 + cpart + rlow * 8] = hb;
        }
        return;
    }

    // ================= attention + edge-input (step t, 48 blocks) =================
    const int rb16n = blockIdx.x;

    __shared__ float q_lds[16][68];
    __shared__ float shbuf[16][260];
    __shared__ float sc_lds[16][12];
    __shared__ float w_lds[16][12];
    __shared__ float qb_lds[16];

    {   // q = h_t @ Wq^T — one jb-tile per wave
        f32x4 qa = (f32x4){0.f, 0.f, 0.f, 0.f};
        #pragma unroll
        for (int kc = 0; kc < 8; ++kc) {
            bf16x8 af = *(const bf16x8*)(A_htf + ((size_t)rb16n * 8 + kc) * 512 + lo8);
            bf16x8 bf = *(const bf16x8*)(Wqf + ((size_t)(wid * 8 + kc)) * 512 + lo8);
            qa = __builtin_amdgcn_mfma_f32_16x16x32_bf16(af, bf, qa, 0, 0, 0);
        }
        int a = wid * 16 + l15;
        #pragma unroll
        for (int r = 0; r < 4; ++r)
            q_lds[(l >> 4) * 4 + r][a] = qa[r] + bq[a];
    }
    __syncthreads();
    {   // qk = q @ Wk — 4 jb-tiles per wave
        f32x4 ka[4];
        #pragma unroll
        for (int j2 = 0; j2 < 4; ++j2) ka[j2] = (f32x4){0.f, 0.f, 0.f, 0.f};
        #pragma unroll
        for (int kc = 0; kc < 2; ++kc) {
            int a0 = kc * 32 + (l >> 4) * 8;
            bf16x8 af;
            #pragma unroll
            for (int e = 0; e < 8; ++e)
                ((u16*)&af)[e] = f2bf(q_lds[l15][a0 + e]);
            #pragma unroll
            for (int j2 = 0; j2 < 4; ++j2) {
                bf16x8 bf = *(const bf16x8*)(Wkqf + ((size_t)((wid * 4 + j2) * 2 + kc)) * 512 + lo8);
                ka[j2] = __builtin_amdgcn_mfma_f32_16x16x32_bf16(af, bf, ka[j2], 0, 0, 0);
            }
        }
        #pragma unroll
        for (int j2 = 0; j2 < 4; ++j2)
            #pragma unroll
            for (int r = 0; r < 4; ++r)
                shbuf[(l >> 4) * 4 + r][(wid * 4 + j2) * 16 + l15] = ka[j2][r];
        if (tid < 16) {
            float s = 0.f;
            for (int a = 0; a < 64; ++a) s = fmaf(q_lds[tid][a], bk[a], s);
            qb_lds[tid] = s;
        }
    }
    __syncthreads();
    if (tid < 176) {   // scores (dense h_s reads)
        int row = tid / 11, kk = tid - row * 11;
        int r = rb16n * 16 + row;
        int srow = (r / 12) * 132 + (r % 12) * 11 + kk;
        const u16* hp = A_hsd + (size_t)srow * 256;
        float s = 0.f;
        for (int k = 0; k < 256; k += 8) {
            u16x8 v = *(const u16x8*)(hp + k);
            #pragma unroll
            for (int e = 0; e < 8; ++e) s = fmaf(shbuf[row][k + e], bf2f(v[e]), s);
        }
        sc_lds[row][kk] = (s + qb_lds[row]) * TEMP_;
    }
    __syncthreads();
    if (tid < 16) {   // softmax over 11
        float m = sc_lds[tid][0];
        #pragma unroll
        for (int kk = 1; kk < 11; ++kk) m = fmaxf(m, sc_lds[tid][kk]);
        float ssum = 0.f;
        float wv[11];
        #pragma unroll
        for (int kk = 0; kk < 11; ++kk) { wv[kk] = __expf(sc_lds[tid][kk] - m); ssum += wv[kk]; }
        float inv = 1.f / ssum;
        #pragma unroll
        for (int kk = 0; kk < 11; ++kk) w_lds[tid][kk] = wv[kk] * inv;
    }
    __syncthreads();
    {   // h_attn -> shbuf
        int row = tid >> 4, c0 = (tid & 15) * 16;
        int r = rb16n * 16 + row;
        int sbase = (r / 12) * 132 + (r % 12) * 11;
        float hacc[16];
        #pragma unroll
        for (int e = 0; e < 16; ++e) hacc[e] = 0.f;
        #pragma unroll
        for (int kk = 0; kk < 11; ++kk) {
            float wv = w_lds[row][kk];
            const u16* hp = A_hsd + (size_t)(sbase + kk) * 256 + c0;
            u16x8 v0 = *(const u16x8*)hp;
            u16x8 v1 = *(const u16x8*)(hp + 8);
            #pragma unroll
            for (int e = 0; e < 8; ++e) {
                hacc[e]     = fmaf(wv, bf2f(v0[e]), hacc[e]);
                hacc[8 + e] = fmaf(wv, bf2f(v1[e]), hacc[8 + e]);
            }
        }
        #pragma unroll
        for (int e = 0; e < 16; ++e) shbuf[row][c0 + e] = hacc[e];
    }
    __syncthreads();
    {   // ein = [h_t | h_attn] @ W_edge^T -> global frag A_ein
        f32x4 ea[2];
        ea[0] = (f32x4){0.f, 0.f, 0.f, 0.f};
        ea[1] = (f32x4){0.f, 0.f, 0.f, 0.f};
        #pragma unroll
        for (int kc = 0; kc < 16; ++kc) {
            bf16x8 af;
            if (kc < 8) {
                af = *(const bf16x8*)(A_htf + ((size_t)rb16n * 8 + kc) * 512 + lo8);
            } else {
                int k0 = (kc - 8) * 32 + (l >> 4) * 8;
                #pragma unroll
                for (int e = 0; e < 8; ++e)
                    ((u16*)&af)[e] = f2bf(shbuf[l15][k0 + e]);
            }
            #pragma unroll
            for (int j2 = 0; j2 < 2; ++j2) {
                bf16x8 bf = *(const bf16x8*)(Wef + ((size_t)((wid * 2 + j2) * 16 + kc)) * 512 + lo8);
                ea[j2] = __builtin_amdgcn_mfma_f32_16x16x32_bf16(af, bf, ea[j2], 0, 0, 0);
            }
        }
        #pragma unroll
        for (int j2 = 0; j2 < 2; ++j2) {
            int cell = (wid * 2 + j2) * 16 + l15;
            #pragma unroll
            for (int r = 0; r < 4; ++r) {
                int row = (l >> 4) * 4 + r;
                float v = ea[j2][r] + b_edge[cell];
                v = v > 0.f ? v : 0.f;
                A_ein[((size_t)rb16n * 4 + (cell >> 5)) * 512
                      + (((cell >> 3) & 3) * 16 + row) * 8 + (cell & 7)] = f2bf(v);
            }
        }
    }
}

// out[b,t,n,q] = hist[t+1] . W_out^T + b_out
__global__ __launch_bounds__(256) void out_kernel(
    const u16* __restrict__ hist1, const float* __restrict__ W_out,
    const float* __restrict__ b_out, float* __restrict__ out)
{
    const int lane = threadIdx.x & 63;
    const int grp = threadIdx.x >> 6;
    for (int ridx = blockIdx.x * 4 + grp; ridx < 32 * 768; ridx += gridDim.x * 4) {
        int t = ridx / 768, row = ridx % 768;
        int b = row / 12, n = row % 12;
        const u16* h = &hist1[(size_t)ridx * 256];
        float hv[4];
        #pragma unroll
        for (int i = 0; i < 4; ++i) hv[i] = bf2f(h[i * 64 + lane]);
        #pragma unroll
        for (int q = 0; q < 5; ++q) {
            float s = 0.f;
            #pragma unroll
            for (int i = 0; i < 4; ++i) s = fmaf(hv[i], W_out[q * 256 + i * 64 + lane], s);
            #pragma unroll
            for (int off = 32; off > 0; off >>= 1) s += __shfl_down(s, off, 64);
            if (lane == 0)
                out[(((size_t)b * T_ + t) * N_ + n) * 5 + q] = s + b_out[q];
        }
    }
}

extern "C" void kernel_launch(void* const* d_in, const int* in_sizes, int n_in,
                              void* d_out, int out_size, void* d_ws, size_t ws_size,
                              hipStream_t stream)
{
    const float* nodes = (const float*)d_in[0];
    const float* et    = (const float*)d_in[1];
    const float* es    = (const float*)d_in[2];
    const float* W_te = (const float*)d_in[3];  const float* b_te = (const float*)d_in[4];
    const float* te_Wih = (const float*)d_in[5]; const float* te_Whh = (const float*)d_in[6];
    const float* te_bih = (const float*)d_in[7]; const float* te_bhh = (const float*)d_in[8];
    const float* W_se = (const float*)d_in[9];  const float* b_se = (const float*)d_in[10];
    const float* se_Wih = (const float*)d_in[11]; const float* se_Whh = (const float*)d_in[12];
    const float* se_bih = (const float*)d_in[13]; const float* se_bhh = (const float*)d_in[14];
    const float* Wq = (const float*)d_in[15]; const float* bq = (const float*)d_in[16];
    const float* Wk = (const float*)d_in[17]; const float* bk = (const float*)d_in[18];
    const float* W_node = (const float*)d_in[19]; const float* b_node = (const float*)d_in[20];
    const float* W_edge = (const float*)d_in[21]; const float* b_edge = (const float*)d_in[22];
    const float* nr_Wih = (const float*)d_in[23]; const float* nr_Whh = (const float*)d_in[24];
    const float* nr_bih = (const float*)d_in[25]; const float* nr_bhh = (const float*)d_in[26];
    const float* W_out = (const float*)d_in[27]; const float* b_out = (const float*)d_in[28];

    char* base = (char*)d_ws;
    size_t off = 0;
    auto A = [&](size_t bytes) { char* p = base + off; off += (bytes + 255) & ~(size_t)255; return p; };

    // zero region: c-states (f32) + t=0 frag h-states (bf16), contiguous
    float* c_t = (float*)A(768 * 256 * 4);
    float* c_s = (float*)A((size_t)8448 * 256 * 4);
    float* c_n = (float*)A(768 * 256 * 4);
    u16* htf0 = (u16*)A(768 * 256 * 2);
    u16* hsf0 = (u16*)A((size_t)8448 * 256 * 2);
    u16* hnf0 = (u16*)A(768 * 256 * 2);
    size_t zero_bytes = off;
    u16* htf1 = (u16*)A(768 * 256 * 2);
    u16* hsf1 = (u16*)A((size_t)8448 * 256 * 2);
    u16* hnf1 = (u16*)A(768 * 256 * 2);
    u16* hsd0 = (u16*)A((size_t)8448 * 256 * 2);
    u16* hsd1 = (u16*)A((size_t)8448 * 256 * 2);
    u16* einf0 = (u16*)A(768 * 128 * 2);
    u16* einf1 = (u16*)A(768 * 128 * 2);
    u16* hist = (u16*)A((size_t)33 * 768 * 256 * 2);
    u16* ninf = (u16*)A((size_t)32 * 768 * 128 * 2);
    u16* Wf_t = (u16*)A(1024 * 384 * 2);
    u16* Wf_s = (u16*)A(1024 * 384 * 2);
    u16* Wf_n = (u16*)A(1024 * 512 * 2);
    float* bs_t = (float*)A(1024 * 4);
    float* bs_s = (float*)A(1024 * 4);
    float* bs_n = (float*)A(1024 * 4);
    u16* Wqf  = (u16*)A(2048 * 8 * 2);
    u16* Wkqf = (u16*)A(2048 * 8 * 2);
    u16* Wef  = (u16*)A(8192 * 8 * 2);
    (void)ws_size;

    hipMemsetAsync(base, 0, zero_bytes, stream);

    prep_kernel<<<256, 256, 0, stream>>>(
        te_Wih, te_Whh, te_bih, te_bhh, se_Wih, se_Whh, se_bih, se_bhh,
        nr_Wih, nr_Whh, nr_bih, nr_bhh, Wq, Wk, W_edge,
        Wf_t, Wf_s, Wf_n, bs_t, bs_s, bs_n, Wqf, Wkqf, Wef);

    emb_nin_kernel<<<1536, 256, 0, stream>>>(nodes, W_node, b_node, ninf);

    u16* htf[2] = {htf0, htf1};
    u16* hsf[2] = {hsf0, hsf1};
    u16* hnf[2] = {hnf0, hnf1};
    u16* hsd[2] = {hsd0, hsd1};
    u16* einf[2] = {einf0, einf1};

    // prologue: lstm(0) only. lstm(s): reads h[s&1], writes h[(s+1)&1], dense hsd[(s+1)&1]
    step_kernel<<<576, 256, 0, stream>>>(
        0, 0, 0,
        es, et, W_se, b_se, W_te, b_te,
        Wf_t, bs_t, Wf_s, bs_s,
        htf[0], htf[1], c_t,
        hsf[0], hsf[1], hsd[1], c_s,
        htf[0], hsd[0], einf[0],
        Wqf, bq, Wkqf, bk, Wef, b_edge,
        ninf, einf[0], Wf_n, bs_n, hnf[0], hnf[1], hist, c_n);

    // D(t): attn(t) [48] || node(t-1) [192, t>=1] || lstm(t+1) [576, t<31]
    for (int t = 0; t < T_; ++t) {
        int nN = (t >= 1) ? 192 : 0;
        int nL = (t < T_ - 1) ? 576 : 0;
        int s = t + 1;
        int m = (t >= 1) ? (t - 1) : 0;
        step_kernel<<<48 + nN + nL, 256, 0, stream>>>(
            48, nN, s,
            es, et, W_se, b_se, W_te, b_te,
            Wf_t, bs_t, Wf_s, bs_s,
            htf[s & 1], htf[(s + 1) & 1], c_t,
            hsf[s & 1], hsf[(s + 1) & 1], hsd[(s + 1) & 1], c_s,
            htf[(t + 1) & 1], hsd[(t + 1) & 1], einf[t & 1],
            Wqf, bq, Wkqf, bk, Wef, b_edge,
            ninf + (size_t)m * 48 * 4 * 512, einf[m & 1], Wf_n, bs_n,
            hnf[m & 1], hnf[(m + 1) & 1], hist + (size_t)(m + 1) * 768 * 256, c_n);
    }

    // tail: node(31)
    {
        int m = T_ - 1;
        step_kernel<<<192, 256, 0, stream>>>(
            0, 192, 0,
            es, et, W_se, b_se, W_te, b_te,
            Wf_t, bs_t, Wf_s, bs_s,
            htf[0], htf[1], c_t,
            hsf[0], hsf[1], hsd[1], c_s,
            htf[0], hsd[0], einf[0],
            Wqf, bq, Wkqf, bk, Wef, b_edge,
            ninf + (size_t)m * 48 * 4 * 512, einf[m & 1], Wf_n, bs_n,
            hnf[m & 1], hnf[(m + 1) & 1], hist + (size_t)(m + 1) * 768 * 256, c_n);
    }

    out_kernel<<<1536, 256, 0, stream>>>(hist + (size_t)768 * 256, W_out, b_out, (float*)d_out);
}